// Round 3
// baseline (5293.064 us; speedup 1.0000x reference)
//
#include <hip/hip_runtime.h>
#include <hip/hip_bf16.h>
#include <math.h>

#define N_ROWS 4096
#define DIM    256
#define NLAYER 4

// ---------------------------------------------------------------------------
// Generic NT GEMM: C[M,256] = A[M,256] @ B[256,256]^T (+bias)(+res)
// ---------------------------------------------------------------------------
__global__ __launch_bounds__(256) void gemm_nt_kernel(
    const float* __restrict__ A, const float* __restrict__ Bm,
    const float* __restrict__ bias, const float* __restrict__ res,
    float* __restrict__ C) {
  __shared__ float As[16][65];
  __shared__ float Bs[16][65];
  const int m0 = blockIdx.x * 64, n0 = blockIdx.y * 64;
  const int tid = threadIdx.x;
  const int tx = tid & 15, ty = tid >> 4;
  float acc[4][4] = {};
  for (int k0 = 0; k0 < DIM; k0 += 16) {
    __syncthreads();
#pragma unroll
    for (int p = 0; p < 4; ++p) {
      int row = ty + p * 16;
      As[tx][row] = A[(size_t)(m0 + row) * DIM + k0 + tx];
      Bs[tx][row] = Bm[(size_t)(n0 + row) * DIM + k0 + tx];
    }
    __syncthreads();
#pragma unroll
    for (int kk = 0; kk < 16; ++kk) {
      float a[4], b[4];
#pragma unroll
      for (int r = 0; r < 4; ++r) a[r] = As[kk][ty + r * 16];
#pragma unroll
      for (int c = 0; c < 4; ++c) b[c] = Bs[kk][tx + c * 16];
#pragma unroll
      for (int r = 0; r < 4; ++r)
#pragma unroll
        for (int c = 0; c < 4; ++c) acc[r][c] = fmaf(a[r], b[c], acc[r][c]);
    }
  }
#pragma unroll
  for (int r = 0; r < 4; ++r) {
    int m = m0 + ty + r * 16;
#pragma unroll
    for (int c = 0; c < 4; ++c) {
      int n = n0 + tx + c * 16;
      float vv = acc[r][c];
      if (bias) vv += bias[n];
      if (res) vv += res[(size_t)m * DIM + n];
      C[(size_t)m * DIM + n] = vv;
    }
  }
}

// ---------------------------------------------------------------------------
// ksum = column sum of K [4096,256] (2-stage, deterministic)
// ---------------------------------------------------------------------------
__global__ void ksum_part_kernel(const float* __restrict__ K,
                                 float* __restrict__ kpart) {
  int d = threadIdx.x, b = blockIdx.x;
  float s = 0.f;
  int base = b * 256;
  for (int n = 0; n < 256; ++n) s += K[(size_t)(base + n) * DIM + d];
  kpart[b * DIM + d] = s;
}
__global__ void ksum_red_kernel(const float* __restrict__ kpart,
                                float* __restrict__ ksum) {
  int d = threadIdx.x;
  float s = 0.f;
  for (int b = 0; b < 16; ++b) s += kpart[b * DIM + d];
  ksum[d] = s;
}

// ---------------------------------------------------------------------------
// Mpart[z] = K[z*512:(z+1)*512,:]^T @ K[...] ; grid(4,4,8)
// ---------------------------------------------------------------------------
__global__ __launch_bounds__(256) void mpart_kernel(const float* __restrict__ K,
                                                    float* __restrict__ Mpart) {
  __shared__ float Ka[32][65];
  __shared__ float Kb[32][65];
  const int a0 = blockIdx.x * 64, b0 = blockIdx.y * 64, z = blockIdx.z;
  const int tid = threadIdx.x;
  const int tx = tid & 15, ty = tid >> 4;
  float acc[4][4] = {};
  for (int nb = 0; nb < 512; nb += 32) {
    __syncthreads();
#pragma unroll
    for (int i = 0; i < 8; ++i) {
      int e = tid + i * 256;
      int nr = e >> 6, cc = e & 63;
      size_t rowoff = (size_t)(z * 512 + nb + nr) * DIM;
      Ka[nr][cc] = K[rowoff + a0 + cc];
      Kb[nr][cc] = K[rowoff + b0 + cc];
    }
    __syncthreads();
#pragma unroll
    for (int kk = 0; kk < 32; ++kk) {
      float a[4], b[4];
#pragma unroll
      for (int r = 0; r < 4; ++r) a[r] = Ka[kk][ty + r * 16];
#pragma unroll
      for (int c = 0; c < 4; ++c) b[c] = Kb[kk][tx + c * 16];
#pragma unroll
      for (int r = 0; r < 4; ++r)
#pragma unroll
        for (int c = 0; c < 4; ++c) acc[r][c] = fmaf(a[r], b[c], acc[r][c]);
    }
  }
#pragma unroll
  for (int r = 0; r < 4; ++r)
#pragma unroll
    for (int c = 0; c < 4; ++c)
      Mpart[((size_t)z << 16) + (size_t)(a0 + ty + r * 16) * DIM + b0 + tx +
            c * 16] = acc[r][c];
}
__global__ void mreduce_kernel(const float* __restrict__ Mp,
                               float* __restrict__ Mm) {
  int e = blockIdx.x * 256 + threadIdx.x;
  float s = 0.f;
#pragma unroll
  for (int z = 0; z < 8; ++z) s += Mp[(size_t)z * 65536 + e];
  Mm[e] = s;
}

// ---------------------------------------------------------------------------
// Per-row att mean / inv-std
// ---------------------------------------------------------------------------
__global__ __launch_bounds__(256) void stats_kernel(
    const float* __restrict__ q, const float* __restrict__ tb,
    const float* __restrict__ ksum, const int* __restrict__ tptr,
    float* __restrict__ meanv, float* __restrict__ istdv) {
  const int wave = threadIdx.x >> 6, lane = threadIdx.x & 63;
  const int row = blockIdx.x * 4 + wave;
  const float4 qv = ((const float4*)(q + (size_t)row * DIM))[lane];
  const float4 tv4 = ((const float4*)(tb + (size_t)row * DIM))[lane];
  const float4 kv = ((const float4*)ksum)[lane];
  float p1 = qv.x * kv.x + qv.y * kv.y + qv.z * kv.z + qv.w * kv.w;
  float p2 = tv4.x * qv.x + tv4.y * qv.y + tv4.z * qv.z + tv4.w * qv.w;
#pragma unroll
  for (int off = 32; off >= 1; off >>= 1) {
    p1 += __shfl_xor(p1, off);
    p2 += __shfl_xor(p2, off);
  }
  if (lane == 0) {
    float tt = (float)tptr[0];
    float sc = 1.f / (16.f * tt);
    float mean = p1 * sc * (1.f / (float)N_ROWS);
    float e2 = p2 * sc * sc * (1.f / (float)N_ROWS);
    float var = fmaxf(e2 - mean * mean, 0.f);
    meanv[row] = mean;
    istdv[row] = 1.f / (sqrtf(var) + 1e-5f);
  }
}

__global__ void prep_kernel(const float* __restrict__ yhat,
                            float* __restrict__ logy) {
  int i = blockIdx.x * 256 + threadIdx.x;
  logy[i] = logf(yhat[i] + 1e-9f);
}

// ---------------------------------------------------------------------------
// Pack (dmask & bmask) into bits: mbits[row*128 + w] bit j = mask[row][w*32+j]
// Masks are int32 on device (harness normalizes integer-family inputs).
// One wave covers 64 consecutive elements -> one __ballot -> 2 words.
// ---------------------------------------------------------------------------
__global__ void maskpack_kernel(const int* __restrict__ dmask,
                                const int* __restrict__ bmask,
                                unsigned int* __restrict__ mbits) {
  int gid = blockIdx.x * 256 + threadIdx.x;
  bool v = (dmask[gid] != 0) && (bmask[gid] != 0);
  unsigned long long bal = __ballot(v);
  if ((threadIdx.x & 63) == 0) {
    int w = gid >> 5;
    mbits[w] = (unsigned int)(bal & 0xffffffffu);
    mbits[w + 1] = (unsigned int)(bal >> 32);
  }
}

// ---------------------------------------------------------------------------
// Flash mean-shift attention. grid 256, block 512 (8 waves).
// ---------------------------------------------------------------------------
__global__ __launch_bounds__(512) void flash_kernel(
    const float* __restrict__ q, const float* __restrict__ kmat,
    const float* __restrict__ vmat, const float* __restrict__ xyzc,
    const float* __restrict__ logy, const float* __restrict__ meanv,
    const float* __restrict__ istdv, const unsigned int* __restrict__ mbits,
    const int* __restrict__ tptr, const float* __restrict__ bwp,
    const float* __restrict__ betap, const int* __restrict__ usestdp,
    const int* __restrict__ selfdp, float* __restrict__ x_att,
    float* __restrict__ xyz_out) {
  __shared__ float4 kt4[32 * 64];  // 32 KiB, swizzled
  __shared__ float w_lds[16][32];
  __shared__ float scl[16];
  __shared__ float s_lds[16];
  __shared__ float xyz_t[32][3];
  __shared__ float sqt[32];
  __shared__ float logyt[32];

  const int tid = threadIdx.x;
  const int wave = tid >> 6, lane = tid & 63;
  const int j = lane & 31;
  const int rh = lane >> 5;
  const int rowbase = blockIdx.x * 16;
  const int row_l = wave * 2 + rh;
  const int grow = rowbase + row_l;

  const float tv = (float)tptr[0];
  const float scale = 1.f / (16.f * tv);
  const float bw = bwp[0];
  const float inv2bw2 = 1.f / (2.f * bw * bw);
  const float betav = betap[0];
  const int usestd = usestdp[0];
  const float selfd = (float)selfdp[0];

  const float mrow = meanv[grow];
  const float irow = istdv[grow];
  const float xr0 = xyzc[(size_t)grow * 3 + 0];
  const float xr1 = xyzc[(size_t)grow * 3 + 1];
  const float xr2 = xyzc[(size_t)grow * 3 + 2];
  const float sqr = xr0 * xr0 + xr1 * xr1 + xr2 * xr2;

  float m = -INFINITY, s = 0.f;
  float acc[2][4] = {};
  float axyz = 0.f;  // lanes 0..5: r=lane&1, ax=lane>>1
  const int xr = lane & 1, xax = lane >> 1;

  const float4* qr = (const float4*)(q + (size_t)grow * DIM);
  const float4* vg = (const float4*)vmat;

  for (int t0 = 0; t0 < N_ROWS; t0 += 32) {
    __syncthreads();
    {
      const float4* kg = (const float4*)(kmat + (size_t)t0 * DIM);
#pragma unroll
      for (int i = 0; i < 4; ++i) {
        int e = tid + i * 512;  // 0..2047
        int jr = e >> 6, cc = e & 63;
        kt4[jr * 64 + (cc ^ (jr & 7))] = kg[e];
      }
      if (tid < 32) {
        int jj = tid;
        float a0 = xyzc[(size_t)(t0 + jj) * 3 + 0];
        float a1 = xyzc[(size_t)(t0 + jj) * 3 + 1];
        float a2 = xyzc[(size_t)(t0 + jj) * 3 + 2];
        xyz_t[jj][0] = a0;
        xyz_t[jj][1] = a1;
        xyz_t[jj][2] = a2;
        sqt[jj] = a0 * a0 + a1 * a1 + a2 * a2;
      } else if (tid < 64) {
        logyt[tid - 32] = logy[t0 + tid - 32];
      }
    }
    __syncthreads();

    // ---- phase 1: score for (grow, t0+j)
    float att = 0.f;
#pragma unroll 8
    for (int c = 0; c < 64; ++c) {
      float4 qv = qr[c];
      float4 kv = kt4[(j << 6) + (c ^ (j & 7))];
      att += qv.x * kv.x + qv.y * kv.y + qv.z * kv.z + qv.w * kv.w;
    }
    att *= scale;
    float a = usestd ? (att - mrow) * irow : att;
    int gj = t0 + j;
    float d3 = xr0 * xyz_t[j][0] + xr1 * xyz_t[j][1] + xr2 * xyz_t[j][2];
    float d2 = sqr + sqt[j] - 2.f * d3;
    d2 = fmaxf(d2, 0.f);
    if (grow == gj) d2 += selfd;
    float logit = a - d2 * inv2bw2 + logyt[j];
    unsigned int mword = mbits[((size_t)grow << 7) + (t0 >> 5)];
    if (!((mword >> j) & 1u)) logit = -1e9f;

    float tmax = logit;
#pragma unroll
    for (int off = 16; off >= 1; off >>= 1)
      tmax = fmaxf(tmax, __shfl_xor(tmax, off));
    float newm = fmaxf(m, tmax);
    float corr = __expf(m - newm);
    float e = __expf(logit - newm);
    float esum = e;
#pragma unroll
    for (int off = 16; off >= 1; off >>= 1) esum += __shfl_xor(esum, off);
    s = s * corr + esum;
    m = newm;
    w_lds[row_l][j] = e;
    if (j == 0) scl[row_l] = corr;

    // ---- phase 2: accumulate w@v for both rows of this wave
    float c0 = scl[wave * 2 + 0];
    float c1 = scl[wave * 2 + 1];
#pragma unroll
    for (int c = 0; c < 4; ++c) {
      acc[0][c] *= c0;
      acc[1][c] *= c1;
    }
#pragma unroll 4
    for (int jj = 0; jj < 32; ++jj) {
      float4 vv = vg[((size_t)(t0 + jj) << 6) + lane];
      float w0 = w_lds[wave * 2 + 0][jj];
      float w1 = w_lds[wave * 2 + 1][jj];
      acc[0][0] = fmaf(w0, vv.x, acc[0][0]);
      acc[0][1] = fmaf(w0, vv.y, acc[0][1]);
      acc[0][2] = fmaf(w0, vv.z, acc[0][2]);
      acc[0][3] = fmaf(w0, vv.w, acc[0][3]);
      acc[1][0] = fmaf(w1, vv.x, acc[1][0]);
      acc[1][1] = fmaf(w1, vv.y, acc[1][1]);
      acc[1][2] = fmaf(w1, vv.z, acc[1][2]);
      acc[1][3] = fmaf(w1, vv.w, acc[1][3]);
    }
    // ---- w @ xyz on 6 lanes
    if (lane < 6) {
      float ax = axyz * ((xr == 0) ? c0 : c1);
      for (int jj = 0; jj < 32; ++jj)
        ax = fmaf(w_lds[wave * 2 + xr][jj], xyz_t[jj][xax], ax);
      axyz = ax;
    }
  }

  if (j == 0) s_lds[row_l] = s;
  __syncthreads();
  float inv0 = 1.f / s_lds[wave * 2 + 0];
  float inv1 = 1.f / s_lds[wave * 2 + 1];
  float4 o0, o1;
  o0.x = acc[0][0] * inv0;
  o0.y = acc[0][1] * inv0;
  o0.z = acc[0][2] * inv0;
  o0.w = acc[0][3] * inv0;
  o1.x = acc[1][0] * inv1;
  o1.y = acc[1][1] * inv1;
  o1.z = acc[1][2] * inv1;
  o1.w = acc[1][3] * inv1;
  ((float4*)(x_att + (size_t)(rowbase + wave * 2 + 0) * DIM))[lane] = o0;
  ((float4*)(x_att + (size_t)(rowbase + wave * 2 + 1) * DIM))[lane] = o1;
  if (lane < 6) {
    int gr = rowbase + wave * 2 + xr;
    float wx = axyz * ((xr == 0) ? inv0 : inv1);
    xyz_out[(size_t)gr * 3 + xax] =
        betav * wx + (1.f - betav) * xyzc[(size_t)gr * 3 + xax];
  }
}

// ---------------------------------------------------------------------------
// GraphNorm
// ---------------------------------------------------------------------------
__global__ void gn_stats_kernel(const float* __restrict__ X,
                                const int* __restrict__ cums,
                                float* __restrict__ gm,
                                float* __restrict__ gi) {
  int b = blockIdx.x, d = threadIdx.x;
  int r0 = cums[b], r1 = cums[b + 1];
  float s = 0.f, ss = 0.f;
  for (int r = r0; r < r1; ++r) {
    float v = X[(size_t)r * DIM + d];
    s += v;
    ss += v * v;
  }
  float cnt = (float)(r1 - r0);
  float mean = s / fmaxf(cnt, 1.f);
  float var = (ss - cnt * mean * mean) / fmaxf(cnt - 1.f, 1.f);
  gm[b * DIM + d] = mean;
  gi[b * DIM + d] = 1.f / (sqrtf(fmaxf(var, 0.f)) + 1e-5f);
}

__global__ __launch_bounds__(256) void gn_apply_kernel(
    const float* __restrict__ X, const float* __restrict__ gamma,
    const float* __restrict__ betag, const int* __restrict__ cums, int nseg,
    const float* __restrict__ gm, const float* __restrict__ gi,
    float* __restrict__ Xout, float* __restrict__ ofinal) {
  int idx = blockIdx.x * 256 + threadIdx.x;  // float4 index
  int base = idx * 4;
  int row = base >> 8, d0 = base & 255;
  int seg = 0;
  for (int b = 1; b <= nseg; ++b) seg += (row >= cums[b]) ? 1 : 0;
  float4 x = ((const float4*)X)[idx];
  float xs[4] = {x.x, x.y, x.z, x.w};
  const float* gmp = gm + seg * DIM + d0;
  const float* gip = gi + seg * DIM + d0;
  float o[4];
#pragma unroll
  for (int c = 0; c < 4; ++c)
    o[c] = gamma[d0 + c] * (xs[c] - gmp[c]) * gip[c] + betag[d0 + c];
  float4 ov = {o[0], o[1], o[2], o[3]};
  ((float4*)Xout)[idx] = ov;
  if (ofinal) ((float4*)ofinal)[idx] = ov;
}

// ---------------------------------------------------------------------------
extern "C" void kernel_launch(void* const* d_in, const int* in_sizes, int n_in,
                              void* d_out, int out_size, void* d_ws,
                              size_t ws_size, hipStream_t stream) {
  const float* xyz0 = (const float*)d_in[0];
  const float* x0 = (const float*)d_in[1];
  const float* yhat = (const float*)d_in[2];
  const int* dmask = (const int*)d_in[3];
  const int* tptr = (const int*)d_in[4];
  const float* bwp = (const float*)d_in[5];
  const float* betap = (const float*)d_in[6];
  const int* cums = (const int*)d_in[7];
  const int* bmask = (const int*)d_in[8];
  const int* usestdp = (const int*)d_in[9];
  const int* selfdp = (const int*)d_in[10];
  const float* qw = (const float*)d_in[11];
  const float* kw = (const float*)d_in[12];
  const float* vw = (const float*)d_in[13];
  const float* ow = (const float*)d_in[14];
  const float* qbv = (const float*)d_in[15];
  const float* kbv = (const float*)d_in[16];
  const float* vbv = (const float*)d_in[17];
  const float* obv = (const float*)d_in[18];
  const float* gamma = (const float*)d_in[19];
  const float* betag = (const float*)d_in[20];
  float* out = (float*)d_out;
  float* ws = (float*)d_ws;

  const size_t ND = (size_t)N_ROWS * DIM;  // 1,048,576
  float* bq = ws + 0 * ND;
  float* bk = ws + 1 * ND;
  float* bv = ws + 2 * ND;
  float* bt = ws + 3 * ND;  // t = Q@M, then reused as x_att
  float* bh = ws + 4 * ND;
  float* bx = ws + 5 * ND;
  float* Mp = ws + 6 * ND;           // 8*65536
  float* Mm = Mp + 8 * 65536;        // 65536
  float* kpart = Mm + 65536;         // 16*256
  float* ksum = kpart + 16 * 256;    // 256
  float* meanv = ksum + 256;         // 4096
  float* istdv = meanv + 4096;       // 4096
  float* gm = istdv + 4096;          // 8*256
  float* gi = gm + 8 * 256;          // 8*256
  float* logy = gi + 8 * 256;        // 4096
  float* xyzA = logy + 4096;         // 4096*3
  float* xyzB = xyzA + 3 * N_ROWS;   // 4096*3
  unsigned int* mbits = (unsigned int*)(xyzB + 3 * N_ROWS);  // 4096*128 u32

  const int nseg = in_sizes[7] - 1;

  prep_kernel<<<16, 256, 0, stream>>>(yhat, logy);
  maskpack_kernel<<<65536, 256, 0, stream>>>(dmask, bmask, mbits);

  for (int l = 0; l < NLAYER; ++l) {
    const float* xin = (l == 0) ? x0 : bx;
    const float* xyz_in = (l == 0) ? xyz0 : ((l & 1) ? xyzB : xyzA);
    float* xyz_o = (l & 1) ? xyzA : xyzB;
    const float* Wq = qw + (size_t)l * DIM * DIM;
    const float* Wk = kw + (size_t)l * DIM * DIM;
    const float* Wv = vw + (size_t)l * DIM * DIM;
    const float* Wo = ow + (size_t)l * DIM * DIM;

    gemm_nt_kernel<<<dim3(64, 4), 256, 0, stream>>>(xin, Wq, qbv + l * DIM,
                                                    nullptr, bq);
    gemm_nt_kernel<<<dim3(64, 4), 256, 0, stream>>>(xin, Wk, kbv + l * DIM,
                                                    nullptr, bk);
    gemm_nt_kernel<<<dim3(64, 4), 256, 0, stream>>>(xin, Wv, vbv + l * DIM,
                                                    nullptr, bv);
    ksum_part_kernel<<<16, 256, 0, stream>>>(bk, kpart);
    ksum_red_kernel<<<1, 256, 0, stream>>>(kpart, ksum);
    mpart_kernel<<<dim3(4, 4, 8), 256, 0, stream>>>(bk, Mp);
    mreduce_kernel<<<256, 256, 0, stream>>>(Mp, Mm);
    gemm_nt_kernel<<<dim3(64, 4), 256, 0, stream>>>(bq, Mm, nullptr, nullptr,
                                                    bt);
    stats_kernel<<<1024, 256, 0, stream>>>(bq, bt, ksum, tptr, meanv, istdv);
    flash_kernel<<<256, 512, 0, stream>>>(bq, bk, bv, xyz_in, logy, meanv,
                                          istdv, mbits, tptr, bwp, betap,
                                          usestdp, selfdp, bt, xyz_o);
    gemm_nt_kernel<<<dim3(64, 4), 256, 0, stream>>>(bt, Wo, obv + l * DIM, xin,
                                                    bh);
    gn_stats_kernel<<<nseg, 256, 0, stream>>>(bh, cums, gm, gi);
    gn_apply_kernel<<<1024, 256, 0, stream>>>(
        bh, gamma + (size_t)l * DIM, betag + (size_t)l * DIM, cums, nseg, gm,
        gi, bx, (l == NLAYER - 1) ? out : nullptr);
  }
}

// Round 4
// 3212.521 us; speedup vs baseline: 1.6476x; 1.6476x over previous
//
#include <hip/hip_runtime.h>
#include <hip/hip_bf16.h>
#include <math.h>

#define N_ROWS 4096
#define DIM    256
#define NLAYER 4
#define KSPLIT 2
#define COLS_PER_SPLIT (N_ROWS / KSPLIT)

// ---------------------------------------------------------------------------
// Generic NT GEMM: C[M,256] = A[M,256] @ B[256,256]^T (+bias)(+res)
// ---------------------------------------------------------------------------
__global__ __launch_bounds__(256) void gemm_nt_kernel(
    const float* __restrict__ A, const float* __restrict__ Bm,
    const float* __restrict__ bias, const float* __restrict__ res,
    float* __restrict__ C) {
  __shared__ float As[16][65];
  __shared__ float Bs[16][65];
  const int m0 = blockIdx.x * 64, n0 = blockIdx.y * 64;
  const int tid = threadIdx.x;
  const int tx = tid & 15, ty = tid >> 4;
  float acc[4][4] = {};
  for (int k0 = 0; k0 < DIM; k0 += 16) {
    __syncthreads();
#pragma unroll
    for (int p = 0; p < 4; ++p) {
      int row = ty + p * 16;
      As[tx][row] = A[(size_t)(m0 + row) * DIM + k0 + tx];
      Bs[tx][row] = Bm[(size_t)(n0 + row) * DIM + k0 + tx];
    }
    __syncthreads();
#pragma unroll
    for (int kk = 0; kk < 16; ++kk) {
      float a[4], b[4];
#pragma unroll
      for (int r = 0; r < 4; ++r) a[r] = As[kk][ty + r * 16];
#pragma unroll
      for (int c = 0; c < 4; ++c) b[c] = Bs[kk][tx + c * 16];
#pragma unroll
      for (int r = 0; r < 4; ++r)
#pragma unroll
        for (int c = 0; c < 4; ++c) acc[r][c] = fmaf(a[r], b[c], acc[r][c]);
    }
  }
#pragma unroll
  for (int r = 0; r < 4; ++r) {
    int m = m0 + ty + r * 16;
#pragma unroll
    for (int c = 0; c < 4; ++c) {
      int n = n0 + tx + c * 16;
      float vv = acc[r][c];
      if (bias) vv += bias[n];
      if (res) vv += res[(size_t)m * DIM + n];
      C[(size_t)m * DIM + n] = vv;
    }
  }
}

// Fused QKV: blockIdx.z selects (W, bias, out)
__global__ __launch_bounds__(256) void gemm_qkv_kernel(
    const float* __restrict__ A, const float* __restrict__ W0,
    const float* __restrict__ W1, const float* __restrict__ W2,
    const float* __restrict__ b0, const float* __restrict__ b1,
    const float* __restrict__ b2, float* __restrict__ C0,
    float* __restrict__ C1, float* __restrict__ C2) {
  const float* Bm = (blockIdx.z == 0) ? W0 : (blockIdx.z == 1) ? W1 : W2;
  const float* bias = (blockIdx.z == 0) ? b0 : (blockIdx.z == 1) ? b1 : b2;
  float* C = (blockIdx.z == 0) ? C0 : (blockIdx.z == 1) ? C1 : C2;
  __shared__ float As[16][65];
  __shared__ float Bs[16][65];
  const int m0 = blockIdx.x * 64, n0 = blockIdx.y * 64;
  const int tid = threadIdx.x;
  const int tx = tid & 15, ty = tid >> 4;
  float acc[4][4] = {};
  for (int k0 = 0; k0 < DIM; k0 += 16) {
    __syncthreads();
#pragma unroll
    for (int p = 0; p < 4; ++p) {
      int row = ty + p * 16;
      As[tx][row] = A[(size_t)(m0 + row) * DIM + k0 + tx];
      Bs[tx][row] = Bm[(size_t)(n0 + row) * DIM + k0 + tx];
    }
    __syncthreads();
#pragma unroll
    for (int kk = 0; kk < 16; ++kk) {
      float a[4], b[4];
#pragma unroll
      for (int r = 0; r < 4; ++r) a[r] = As[kk][ty + r * 16];
#pragma unroll
      for (int c = 0; c < 4; ++c) b[c] = Bs[kk][tx + c * 16];
#pragma unroll
      for (int r = 0; r < 4; ++r)
#pragma unroll
        for (int c = 0; c < 4; ++c) acc[r][c] = fmaf(a[r], b[c], acc[r][c]);
    }
  }
#pragma unroll
  for (int r = 0; r < 4; ++r) {
    int m = m0 + ty + r * 16;
#pragma unroll
    for (int c = 0; c < 4; ++c) {
      int n = n0 + tx + c * 16;
      C[(size_t)m * DIM + n] = acc[r][c] + bias[n];
    }
  }
}

// ---------------------------------------------------------------------------
// ksum = column sum of K (2-stage)
// ---------------------------------------------------------------------------
__global__ void ksum_part_kernel(const float* __restrict__ K,
                                 float* __restrict__ kpart) {
  int d = threadIdx.x, b = blockIdx.x;
  float s = 0.f;
  int base = b * 256;
  for (int n = 0; n < 256; ++n) s += K[(size_t)(base + n) * DIM + d];
  kpart[b * DIM + d] = s;
}
__global__ void ksum_red_kernel(const float* __restrict__ kpart,
                                float* __restrict__ ksum) {
  int d = threadIdx.x;
  float s = 0.f;
  for (int b = 0; b < 16; ++b) s += kpart[b * DIM + d];
  ksum[d] = s;
}

// ---------------------------------------------------------------------------
// Mpart[z] = K[z*512:(z+1)*512,:]^T @ K[...] ; grid(4,4,8)
// ---------------------------------------------------------------------------
__global__ __launch_bounds__(256) void mpart_kernel(const float* __restrict__ K,
                                                    float* __restrict__ Mpart) {
  __shared__ float Ka[32][65];
  __shared__ float Kb[32][65];
  const int a0 = blockIdx.x * 64, b0 = blockIdx.y * 64, z = blockIdx.z;
  const int tid = threadIdx.x;
  const int tx = tid & 15, ty = tid >> 4;
  float acc[4][4] = {};
  for (int nb = 0; nb < 512; nb += 32) {
    __syncthreads();
#pragma unroll
    for (int i = 0; i < 8; ++i) {
      int e = tid + i * 256;
      int nr = e >> 6, cc = e & 63;
      size_t rowoff = (size_t)(z * 512 + nb + nr) * DIM;
      Ka[nr][cc] = K[rowoff + a0 + cc];
      Kb[nr][cc] = K[rowoff + b0 + cc];
    }
    __syncthreads();
#pragma unroll
    for (int kk = 0; kk < 32; ++kk) {
      float a[4], b[4];
#pragma unroll
      for (int r = 0; r < 4; ++r) a[r] = Ka[kk][ty + r * 16];
#pragma unroll
      for (int c = 0; c < 4; ++c) b[c] = Kb[kk][tx + c * 16];
#pragma unroll
      for (int r = 0; r < 4; ++r)
#pragma unroll
        for (int c = 0; c < 4; ++c) acc[r][c] = fmaf(a[r], b[c], acc[r][c]);
    }
  }
#pragma unroll
  for (int r = 0; r < 4; ++r)
#pragma unroll
    for (int c = 0; c < 4; ++c)
      Mpart[((size_t)z << 16) + (size_t)(a0 + ty + r * 16) * DIM + b0 + tx +
            c * 16] = acc[r][c];
}
__global__ void mreduce_kernel(const float* __restrict__ Mp,
                               float* __restrict__ Mm) {
  int e = blockIdx.x * 256 + threadIdx.x;
  float s = 0.f;
#pragma unroll
  for (int z = 0; z < 8; ++z) s += Mp[(size_t)z * 65536 + e];
  Mm[e] = s;
}

// ---------------------------------------------------------------------------
// Per-row att mean / inv-std
// ---------------------------------------------------------------------------
__global__ __launch_bounds__(256) void stats_kernel(
    const float* __restrict__ q, const float* __restrict__ tb,
    const float* __restrict__ ksum, const int* __restrict__ tptr,
    float* __restrict__ meanv, float* __restrict__ istdv) {
  const int wave = threadIdx.x >> 6, lane = threadIdx.x & 63;
  const int row = blockIdx.x * 4 + wave;
  const float4 qv = ((const float4*)(q + (size_t)row * DIM))[lane];
  const float4 tv4 = ((const float4*)(tb + (size_t)row * DIM))[lane];
  const float4 kv = ((const float4*)ksum)[lane];
  float p1 = qv.x * kv.x + qv.y * kv.y + qv.z * kv.z + qv.w * kv.w;
  float p2 = tv4.x * qv.x + tv4.y * qv.y + tv4.z * qv.z + tv4.w * qv.w;
#pragma unroll
  for (int off = 32; off >= 1; off >>= 1) {
    p1 += __shfl_xor(p1, off);
    p2 += __shfl_xor(p2, off);
  }
  if (lane == 0) {
    float tt = (float)tptr[0];
    float sc = 1.f / (16.f * tt);
    float mean = p1 * sc * (1.f / (float)N_ROWS);
    float e2 = p2 * sc * sc * (1.f / (float)N_ROWS);
    float var = fmaxf(e2 - mean * mean, 0.f);
    meanv[row] = mean;
    istdv[row] = 1.f / (sqrtf(var) + 1e-5f);
  }
}

__global__ void prep_kernel(const float* __restrict__ yhat,
                            float* __restrict__ logy) {
  int i = blockIdx.x * 256 + threadIdx.x;
  logy[i] = logf(yhat[i] + 1e-9f);
}

// ---------------------------------------------------------------------------
// Pack (dmask & bmask) into bits (masks are int32 on device)
// ---------------------------------------------------------------------------
__global__ void maskpack_kernel(const int* __restrict__ dmask,
                                const int* __restrict__ bmask,
                                unsigned int* __restrict__ mbits) {
  int gid = blockIdx.x * 256 + threadIdx.x;
  bool v = (dmask[gid] != 0) && (bmask[gid] != 0);
  unsigned long long bal = __ballot(v);
  if ((threadIdx.x & 63) == 0) {
    int w = gid >> 5;
    mbits[w] = (unsigned int)(bal & 0xffffffffu);
    mbits[w + 1] = (unsigned int)(bal >> 32);
  }
}

// ---------------------------------------------------------------------------
// Flash mean-shift attention with K-split. grid (256, KSPLIT), block 512.
// Block: 16 rows x 2048 cols. Outputs raw partials (acc, m, s, axyz).
// K tile col-major xor-swizzled in LDS (conflict-free b128 reads);
// Q rows staged in LDS once (broadcast reads).
// ---------------------------------------------------------------------------
__global__ __launch_bounds__(512) void flash_kernel(
    const float* __restrict__ q, const float* __restrict__ kmat,
    const float* __restrict__ vmat, const float* __restrict__ xyzc,
    const float* __restrict__ logy, const float* __restrict__ meanv,
    const float* __restrict__ istdv, const unsigned int* __restrict__ mbits,
    const int* __restrict__ tptr, const float* __restrict__ bwp,
    const int* __restrict__ usestdp, const int* __restrict__ selfdp,
    float* __restrict__ pacc, float* __restrict__ pm, float* __restrict__ ps,
    float* __restrict__ pax) {
  __shared__ float4 kc4[32 * 64];   // 32 KiB: [c4][j^(c4&31)]
  __shared__ float4 q_lds[16 * 64]; // 16 KiB: [row][c4]
  __shared__ float w_lds[16][32];
  __shared__ float scl[16];
  __shared__ float s_lds[16];
  __shared__ float xyz_t[32][3];
  __shared__ float sqt[32];
  __shared__ float logyt[32];

  const int tid = threadIdx.x;
  const int wave = tid >> 6, lane = tid & 63;
  const int j = lane & 31;
  const int rh = lane >> 5;
  const int rowbase = blockIdx.x * 16;
  const int split = blockIdx.y;
  const int colbase = split * COLS_PER_SPLIT;
  const int row_l = wave * 2 + rh;
  const int grow = rowbase + row_l;

  const float tv = (float)tptr[0];
  const float scale = 1.f / (16.f * tv);
  const float bw = bwp[0];
  const float inv2bw2 = 1.f / (2.f * bw * bw);
  const int usestd = usestdp[0];
  const float selfd = (float)selfdp[0];

  const float mrow = meanv[grow];
  const float irow = istdv[grow];
  const float xr0 = xyzc[(size_t)grow * 3 + 0];
  const float xr1 = xyzc[(size_t)grow * 3 + 1];
  const float xr2 = xyzc[(size_t)grow * 3 + 2];
  const float sqr = xr0 * xr0 + xr1 * xr1 + xr2 * xr2;

  // stage Q rows once
  {
    const float4* qg = (const float4*)(q + (size_t)rowbase * DIM);
#pragma unroll
    for (int i = 0; i < 2; ++i) q_lds[tid + i * 512] = qg[tid + i * 512];
  }

  float m = -INFINITY, s = 0.f;
  float acc[2][4] = {};
  float axyz = 0.f;  // lanes 0..5: r=lane&1, ax=lane>>1
  const int xr = lane & 1, xax = lane >> 1;

  const float4* vg = (const float4*)vmat;

  for (int tt0 = 0; tt0 < COLS_PER_SPLIT; tt0 += 32) {
    const int t0 = colbase + tt0;
    __syncthreads();
    {
      const float4* kg = (const float4*)(kmat + (size_t)t0 * DIM);
#pragma unroll
      for (int i = 0; i < 4; ++i) {
        int e = tid + i * 512;  // 0..2047
        int jr = e >> 6, c4 = e & 63;
        kc4[(c4 << 5) + (jr ^ (c4 & 31))] = kg[e];
      }
      if (tid < 32) {
        int jj = tid;
        float a0 = xyzc[(size_t)(t0 + jj) * 3 + 0];
        float a1 = xyzc[(size_t)(t0 + jj) * 3 + 1];
        float a2 = xyzc[(size_t)(t0 + jj) * 3 + 2];
        xyz_t[jj][0] = a0;
        xyz_t[jj][1] = a1;
        xyz_t[jj][2] = a2;
        sqt[jj] = a0 * a0 + a1 * a1 + a2 * a2;
      } else if (tid < 64) {
        logyt[tid - 32] = logy[t0 + tid - 32];
      }
    }
    __syncthreads();

    // ---- phase 1: score for (grow, t0+j); 4 independent FMA chains
    float a0 = 0.f, a1 = 0.f, a2 = 0.f, a3 = 0.f;
#pragma unroll 8
    for (int c4 = 0; c4 < 64; ++c4) {
      float4 qv = q_lds[(row_l << 6) + c4];
      float4 kv = kc4[(c4 << 5) + (j ^ (c4 & 31))];
      a0 = fmaf(qv.x, kv.x, a0);
      a1 = fmaf(qv.y, kv.y, a1);
      a2 = fmaf(qv.z, kv.z, a2);
      a3 = fmaf(qv.w, kv.w, a3);
    }
    float att = ((a0 + a1) + (a2 + a3)) * scale;
    float av = usestd ? (att - mrow) * irow : att;
    int gj = t0 + j;
    float d3 = xr0 * xyz_t[j][0] + xr1 * xyz_t[j][1] + xr2 * xyz_t[j][2];
    float d2 = sqr + sqt[j] - 2.f * d3;
    d2 = fmaxf(d2, 0.f);
    if (grow == gj) d2 += selfd;
    float logit = av - d2 * inv2bw2 + logyt[j];
    unsigned int mword = mbits[((size_t)grow << 7) + (t0 >> 5)];
    if (!((mword >> j) & 1u)) logit = -1e9f;

    float tmax = logit;
#pragma unroll
    for (int off = 16; off >= 1; off >>= 1)
      tmax = fmaxf(tmax, __shfl_xor(tmax, off));
    float newm = fmaxf(m, tmax);
    float corr = __expf(m - newm);
    float e = __expf(logit - newm);
    float esum = e;
#pragma unroll
    for (int off = 16; off >= 1; off >>= 1) esum += __shfl_xor(esum, off);
    s = s * corr + esum;
    m = newm;
    w_lds[row_l][j] = e;
    if (j == 0) scl[row_l] = corr;

    // ---- phase 2: w@v for both rows of this wave (lane -> d-slot)
    float c0 = scl[wave * 2 + 0];
    float c1 = scl[wave * 2 + 1];
#pragma unroll
    for (int c = 0; c < 4; ++c) {
      acc[0][c] *= c0;
      acc[1][c] *= c1;
    }
#pragma unroll 4
    for (int jj = 0; jj < 32; ++jj) {
      float4 vv = vg[((size_t)(t0 + jj) << 6) + lane];
      float w0 = w_lds[wave * 2 + 0][jj];
      float w1 = w_lds[wave * 2 + 1][jj];
      acc[0][0] = fmaf(w0, vv.x, acc[0][0]);
      acc[0][1] = fmaf(w0, vv.y, acc[0][1]);
      acc[0][2] = fmaf(w0, vv.z, acc[0][2]);
      acc[0][3] = fmaf(w0, vv.w, acc[0][3]);
      acc[1][0] = fmaf(w1, vv.x, acc[1][0]);
      acc[1][1] = fmaf(w1, vv.y, acc[1][1]);
      acc[1][2] = fmaf(w1, vv.z, acc[1][2]);
      acc[1][3] = fmaf(w1, vv.w, acc[1][3]);
    }
    // ---- w @ xyz on 6 lanes
    if (lane < 6) {
      float ax = axyz * ((xr == 0) ? c0 : c1);
      for (int jj = 0; jj < 32; ++jj)
        ax = fmaf(w_lds[wave * 2 + xr][jj], xyz_t[jj][xax], ax);
      axyz = ax;
    }
  }

  // write raw partials
  float4 o0 = {acc[0][0], acc[0][1], acc[0][2], acc[0][3]};
  float4 o1 = {acc[1][0], acc[1][1], acc[1][2], acc[1][3]};
  float4* pa = (float4*)pacc;
  pa[((size_t)split * N_ROWS + rowbase + wave * 2 + 0) * 64 + lane] = o0;
  pa[((size_t)split * N_ROWS + rowbase + wave * 2 + 1) * 64 + lane] = o1;
  if (j == 0) {
    pm[(size_t)split * N_ROWS + grow] = m;
    ps[(size_t)split * N_ROWS + grow] = s;
  }
  if (lane < 6) {
    int gr = rowbase + wave * 2 + xr;
    pax[((size_t)split * N_ROWS + gr) * 3 + xax] = axyz;
  }
}

// ---------------------------------------------------------------------------
// Merge KSPLIT partials: x_att = sum_k acc_k*exp(m_k-mg) / sg ; xyz update
// block 256 = 4 rows (wave per row)
// ---------------------------------------------------------------------------
__global__ __launch_bounds__(256) void merge_kernel(
    const float* __restrict__ pacc, const float* __restrict__ pm,
    const float* __restrict__ ps, const float* __restrict__ pax,
    const float* __restrict__ xyzc, const float* __restrict__ betap,
    float* __restrict__ x_att, float* __restrict__ xyz_out) {
  const int wave = threadIdx.x >> 6, lane = threadIdx.x & 63;
  const int row = blockIdx.x * 4 + wave;
  const float4* pa = (const float4*)pacc;
  float4 a0 = pa[(size_t)row * 64 + lane];
  float4 a1 = pa[((size_t)N_ROWS + row) * 64 + lane];
  float m0 = pm[row], m1 = pm[N_ROWS + row];
  float s0 = ps[row], s1 = ps[N_ROWS + row];
  float mg = fmaxf(m0, m1);
  float f0 = __expf(m0 - mg), f1 = __expf(m1 - mg);
  float inv = 1.f / (s0 * f0 + s1 * f1);
  float4 o;
  o.x = (a0.x * f0 + a1.x * f1) * inv;
  o.y = (a0.y * f0 + a1.y * f1) * inv;
  o.z = (a0.z * f0 + a1.z * f1) * inv;
  o.w = (a0.w * f0 + a1.w * f1) * inv;
  ((float4*)(x_att + (size_t)row * DIM))[lane] = o;
  if (lane < 3) {
    float ax = (pax[(size_t)row * 3 + lane] * f0 +
                pax[((size_t)N_ROWS + row) * 3 + lane] * f1) *
               inv;
    float beta = betap[0];
    xyz_out[(size_t)row * 3 + lane] =
        beta * ax + (1.f - beta) * xyzc[(size_t)row * 3 + lane];
  }
}

// ---------------------------------------------------------------------------
// GraphNorm
// ---------------------------------------------------------------------------
__global__ void gn_stats_kernel(const float* __restrict__ X,
                                const int* __restrict__ cums,
                                float* __restrict__ gm,
                                float* __restrict__ gi) {
  int b = blockIdx.x, d = threadIdx.x;
  int r0 = cums[b], r1 = cums[b + 1];
  float s = 0.f, ss = 0.f;
  for (int r = r0; r < r1; ++r) {
    float v = X[(size_t)r * DIM + d];
    s += v;
    ss += v * v;
  }
  float cnt = (float)(r1 - r0);
  float mean = s / fmaxf(cnt, 1.f);
  float var = (ss - cnt * mean * mean) / fmaxf(cnt - 1.f, 1.f);
  gm[b * DIM + d] = mean;
  gi[b * DIM + d] = 1.f / (sqrtf(fmaxf(var, 0.f)) + 1e-5f);
}

__global__ __launch_bounds__(256) void gn_apply_kernel(
    const float* __restrict__ X, const float* __restrict__ gamma,
    const float* __restrict__ betag, const int* __restrict__ cums, int nseg,
    const float* __restrict__ gm, const float* __restrict__ gi,
    float* __restrict__ Xout, float* __restrict__ ofinal) {
  int idx = blockIdx.x * 256 + threadIdx.x;  // float4 index
  int base = idx * 4;
  int row = base >> 8, d0 = base & 255;
  int seg = 0;
  for (int b = 1; b <= nseg; ++b) seg += (row >= cums[b]) ? 1 : 0;
  float4 x = ((const float4*)X)[idx];
  float xs[4] = {x.x, x.y, x.z, x.w};
  const float* gmp = gm + seg * DIM + d0;
  const float* gip = gi + seg * DIM + d0;
  float o[4];
#pragma unroll
  for (int c = 0; c < 4; ++c)
    o[c] = gamma[d0 + c] * (xs[c] - gmp[c]) * gip[c] + betag[d0 + c];
  float4 ov = {o[0], o[1], o[2], o[3]};
  ((float4*)Xout)[idx] = ov;
  if (ofinal) ((float4*)ofinal)[idx] = ov;
}

// ---------------------------------------------------------------------------
extern "C" void kernel_launch(void* const* d_in, const int* in_sizes, int n_in,
                              void* d_out, int out_size, void* d_ws,
                              size_t ws_size, hipStream_t stream) {
  const float* xyz0 = (const float*)d_in[0];
  const float* x0 = (const float*)d_in[1];
  const float* yhat = (const float*)d_in[2];
  const int* dmask = (const int*)d_in[3];
  const int* tptr = (const int*)d_in[4];
  const float* bwp = (const float*)d_in[5];
  const float* betap = (const float*)d_in[6];
  const int* cums = (const int*)d_in[7];
  const int* bmask = (const int*)d_in[8];
  const int* usestdp = (const int*)d_in[9];
  const int* selfdp = (const int*)d_in[10];
  const float* qw = (const float*)d_in[11];
  const float* kw = (const float*)d_in[12];
  const float* vw = (const float*)d_in[13];
  const float* ow = (const float*)d_in[14];
  const float* qbv = (const float*)d_in[15];
  const float* kbv = (const float*)d_in[16];
  const float* vbv = (const float*)d_in[17];
  const float* obv = (const float*)d_in[18];
  const float* gamma = (const float*)d_in[19];
  const float* betag = (const float*)d_in[20];
  float* out = (float*)d_out;
  float* ws = (float*)d_ws;

  const size_t ND = (size_t)N_ROWS * DIM;  // 1,048,576
  float* bq = ws + 0 * ND;
  float* bk = ws + 1 * ND;
  float* bv = ws + 2 * ND;
  float* bt = ws + 3 * ND;   // Q@M for stats; then pacc split 0
  float* bh = ws + 4 * ND;   // pacc split 1; then O-proj output
  float* bx = ws + 5 * ND;   // layer output
  float* pacc = bt;          // spans bt..bh (2*ND)
  float* Mp = ws + 6 * ND;           // 8*65536
  float* Mm = Mp + 8 * 65536;        // 65536
  float* kpart = Mm + 65536;         // 16*256
  float* ksum = kpart + 16 * 256;    // 256
  float* meanv = ksum + 256;         // 4096
  float* istdv = meanv + 4096;       // 4096
  float* gm = istdv + 4096;          // 8*256
  float* gi = gm + 8 * 256;          // 8*256
  float* logy = gi + 8 * 256;        // 4096
  float* xyzA = logy + 4096;         // 4096*3
  float* xyzB = xyzA + 3 * N_ROWS;   // 4096*3
  unsigned int* mbits = (unsigned int*)(xyzB + 3 * N_ROWS);  // 4096*128 u32
  float* pm = (float*)(mbits + (size_t)N_ROWS * 128);        // 2*4096
  float* ps = pm + KSPLIT * N_ROWS;                          // 2*4096
  float* pax = ps + KSPLIT * N_ROWS;                         // 2*4096*3

  const int nseg = in_sizes[7] - 1;

  prep_kernel<<<16, 256, 0, stream>>>(yhat, logy);
  maskpack_kernel<<<65536, 256, 0, stream>>>(dmask, bmask, mbits);

  for (int l = 0; l < NLAYER; ++l) {
    const float* xin = (l == 0) ? x0 : bx;
    const float* xyz_in = (l == 0) ? xyz0 : ((l & 1) ? xyzB : xyzA);
    float* xyz_o = (l & 1) ? xyzA : xyzB;
    const float* Wq = qw + (size_t)l * DIM * DIM;
    const float* Wk = kw + (size_t)l * DIM * DIM;
    const float* Wv = vw + (size_t)l * DIM * DIM;
    const float* Wo = ow + (size_t)l * DIM * DIM;

    gemm_qkv_kernel<<<dim3(64, 4, 3), 256, 0, stream>>>(
        xin, Wq, Wk, Wv, qbv + l * DIM, kbv + l * DIM, vbv + l * DIM, bq, bk,
        bv);
    ksum_part_kernel<<<16, 256, 0, stream>>>(bk, kpart);
    ksum_red_kernel<<<1, 256, 0, stream>>>(kpart, ksum);
    mpart_kernel<<<dim3(4, 4, 8), 256, 0, stream>>>(bk, Mp);
    mreduce_kernel<<<256, 256, 0, stream>>>(Mp, Mm);
    gemm_nt_kernel<<<dim3(64, 4), 256, 0, stream>>>(bq, Mm, nullptr, nullptr,
                                                    bt);
    stats_kernel<<<1024, 256, 0, stream>>>(bq, bt, ksum, tptr, meanv, istdv);
    flash_kernel<<<dim3(256, KSPLIT), 512, 0, stream>>>(
        bq, bk, bv, xyz_in, logy, meanv, istdv, mbits, tptr, bwp, usestdp,
        selfdp, pacc, pm, ps, pax);
    merge_kernel<<<1024, 256, 0, stream>>>(pacc, pm, ps, pax, xyz_in, betap,
                                           bv, xyz_o);
    gemm_nt_kernel<<<dim3(64, 4), 256, 0, stream>>>(bv, Wo, obv + l * DIM, xin,
                                                    bh);
    gn_stats_kernel<<<nseg, 256, 0, stream>>>(bh, cums, gm, gi);
    gn_apply_kernel<<<1024, 256, 0, stream>>>(
        bh, gamma + (size_t)l * DIM, betag + (size_t)l * DIM, cums, nseg, gm,
        gi, bx, (l == NLAYER - 1) ? out : nullptr);
  }
}

// Round 5
// 1552.304 us; speedup vs baseline: 3.4098x; 2.0695x over previous
//
#include <hip/hip_runtime.h>
#include <hip/hip_bf16.h>
#include <math.h>

#define N_ROWS 4096
#define DIM    256
#define NLAYER 4
#define KSPLIT 8
#define COLS_PER_SPLIT (N_ROWS / KSPLIT)
#define QBLK 64
#define KBLK 32

typedef __attribute__((ext_vector_type(8))) short bf16x8;
typedef __attribute__((ext_vector_type(4))) short bf16x4;
typedef __attribute__((ext_vector_type(4))) float f32x4;

__device__ __forceinline__ unsigned short f2b(float f) {
  unsigned int u = __float_as_uint(f);
  unsigned int r = (u + 0x7fffu + ((u >> 16) & 1u)) >> 16;
  return (unsigned short)r;
}

// ---------------------------------------------------------------------------
// Generic NT GEMM: C[M,256] = A[M,256] @ B[256,256]^T (+bias)(+res)
// ---------------------------------------------------------------------------
__global__ __launch_bounds__(256) void gemm_nt_kernel(
    const float* __restrict__ A, const float* __restrict__ Bm,
    const float* __restrict__ bias, const float* __restrict__ res,
    float* __restrict__ C) {
  __shared__ float As[16][65];
  __shared__ float Bs[16][65];
  const int m0 = blockIdx.x * 64, n0 = blockIdx.y * 64;
  const int tid = threadIdx.x;
  const int tx = tid & 15, ty = tid >> 4;
  float acc[4][4] = {};
  for (int k0 = 0; k0 < DIM; k0 += 16) {
    __syncthreads();
#pragma unroll
    for (int p = 0; p < 4; ++p) {
      int row = ty + p * 16;
      As[tx][row] = A[(size_t)(m0 + row) * DIM + k0 + tx];
      Bs[tx][row] = Bm[(size_t)(n0 + row) * DIM + k0 + tx];
    }
    __syncthreads();
#pragma unroll
    for (int kk = 0; kk < 16; ++kk) {
      float a[4], b[4];
#pragma unroll
      for (int r = 0; r < 4; ++r) a[r] = As[kk][ty + r * 16];
#pragma unroll
      for (int c = 0; c < 4; ++c) b[c] = Bs[kk][tx + c * 16];
#pragma unroll
      for (int r = 0; r < 4; ++r)
#pragma unroll
        for (int c = 0; c < 4; ++c) acc[r][c] = fmaf(a[r], b[c], acc[r][c]);
    }
  }
#pragma unroll
  for (int r = 0; r < 4; ++r) {
    int m = m0 + ty + r * 16;
#pragma unroll
    for (int c = 0; c < 4; ++c) {
      int n = n0 + tx + c * 16;
      float vv = acc[r][c];
      if (bias) vv += bias[n];
      if (res) vv += res[(size_t)m * DIM + n];
      C[(size_t)m * DIM + n] = vv;
    }
  }
}

// Fused QKV with bf16 side-outputs for Q and K
__global__ __launch_bounds__(256) void gemm_qkv_kernel(
    const float* __restrict__ A, const float* __restrict__ W0,
    const float* __restrict__ W1, const float* __restrict__ W2,
    const float* __restrict__ b0, const float* __restrict__ b1,
    const float* __restrict__ b2, float* __restrict__ C0,
    float* __restrict__ C1, float* __restrict__ C2,
    unsigned short* __restrict__ Qb16, unsigned short* __restrict__ Kb16) {
  const float* Bm = (blockIdx.z == 0) ? W0 : (blockIdx.z == 1) ? W1 : W2;
  const float* bias = (blockIdx.z == 0) ? b0 : (blockIdx.z == 1) ? b1 : b2;
  float* C = (blockIdx.z == 0) ? C0 : (blockIdx.z == 1) ? C1 : C2;
  unsigned short* Cb =
      (blockIdx.z == 0) ? Qb16 : (blockIdx.z == 1) ? Kb16 : nullptr;
  __shared__ float As[16][65];
  __shared__ float Bs[16][65];
  const int m0 = blockIdx.x * 64, n0 = blockIdx.y * 64;
  const int tid = threadIdx.x;
  const int tx = tid & 15, ty = tid >> 4;
  float acc[4][4] = {};
  for (int k0 = 0; k0 < DIM; k0 += 16) {
    __syncthreads();
#pragma unroll
    for (int p = 0; p < 4; ++p) {
      int row = ty + p * 16;
      As[tx][row] = A[(size_t)(m0 + row) * DIM + k0 + tx];
      Bs[tx][row] = Bm[(size_t)(n0 + row) * DIM + k0 + tx];
    }
    __syncthreads();
#pragma unroll
    for (int kk = 0; kk < 16; ++kk) {
      float a[4], b[4];
#pragma unroll
      for (int r = 0; r < 4; ++r) a[r] = As[kk][ty + r * 16];
#pragma unroll
      for (int c = 0; c < 4; ++c) b[c] = Bs[kk][tx + c * 16];
#pragma unroll
      for (int r = 0; r < 4; ++r)
#pragma unroll
        for (int c = 0; c < 4; ++c) acc[r][c] = fmaf(a[r], b[c], acc[r][c]);
    }
  }
#pragma unroll
  for (int r = 0; r < 4; ++r) {
    int m = m0 + ty + r * 16;
#pragma unroll
    for (int c = 0; c < 4; ++c) {
      int n = n0 + tx + c * 16;
      float vv = acc[r][c] + bias[n];
      C[(size_t)m * DIM + n] = vv;
      if (Cb) Cb[(size_t)m * DIM + n] = f2b(vv);
    }
  }
}

// ---------------------------------------------------------------------------
// ksum = column sum of K (2-stage)
// ---------------------------------------------------------------------------
__global__ void ksum_part_kernel(const float* __restrict__ K,
                                 float* __restrict__ kpart) {
  int d = threadIdx.x, b = blockIdx.x;
  float s = 0.f;
  int base = b * 256;
  for (int n = 0; n < 256; ++n) s += K[(size_t)(base + n) * DIM + d];
  kpart[b * DIM + d] = s;
}
__global__ void ksum_red_kernel(const float* __restrict__ kpart,
                                float* __restrict__ ksum) {
  int d = threadIdx.x;
  float s = 0.f;
  for (int b = 0; b < 16; ++b) s += kpart[b * DIM + d];
  ksum[d] = s;
}

// ---------------------------------------------------------------------------
// Mpart[z] = K[z*512:(z+1)*512,:]^T @ K[...] ; grid(4,4,8)
// ---------------------------------------------------------------------------
__global__ __launch_bounds__(256) void mpart_kernel(const float* __restrict__ K,
                                                    float* __restrict__ Mpart) {
  __shared__ float Ka[32][65];
  __shared__ float Kb[32][65];
  const int a0 = blockIdx.x * 64, b0 = blockIdx.y * 64, z = blockIdx.z;
  const int tid = threadIdx.x;
  const int tx = tid & 15, ty = tid >> 4;
  float acc[4][4] = {};
  for (int nb = 0; nb < 512; nb += 32) {
    __syncthreads();
#pragma unroll
    for (int i = 0; i < 8; ++i) {
      int e = tid + i * 256;
      int nr = e >> 6, cc = e & 63;
      size_t rowoff = (size_t)(z * 512 + nb + nr) * DIM;
      Ka[nr][cc] = K[rowoff + a0 + cc];
      Kb[nr][cc] = K[rowoff + b0 + cc];
    }
    __syncthreads();
#pragma unroll
    for (int kk = 0; kk < 32; ++kk) {
      float a[4], b[4];
#pragma unroll
      for (int r = 0; r < 4; ++r) a[r] = Ka[kk][ty + r * 16];
#pragma unroll
      for (int c = 0; c < 4; ++c) b[c] = Kb[kk][tx + c * 16];
#pragma unroll
      for (int r = 0; r < 4; ++r)
#pragma unroll
        for (int c = 0; c < 4; ++c) acc[r][c] = fmaf(a[r], b[c], acc[r][c]);
    }
  }
#pragma unroll
  for (int r = 0; r < 4; ++r)
#pragma unroll
    for (int c = 0; c < 4; ++c)
      Mpart[((size_t)z << 16) + (size_t)(a0 + ty + r * 16) * DIM + b0 + tx +
            c * 16] = acc[r][c];
}
__global__ void mreduce_kernel(const float* __restrict__ Mp,
                               float* __restrict__ Mm) {
  int e = blockIdx.x * 256 + threadIdx.x;
  float s = 0.f;
#pragma unroll
  for (int z = 0; z < 8; ++z) s += Mp[(size_t)z * 65536 + e];
  Mm[e] = s;
}

// ---------------------------------------------------------------------------
// Per-row att mean / inv-std
// ---------------------------------------------------------------------------
__global__ __launch_bounds__(256) void stats_kernel(
    const float* __restrict__ q, const float* __restrict__ tb,
    const float* __restrict__ ksum, const int* __restrict__ tptr,
    float* __restrict__ meanv, float* __restrict__ istdv) {
  const int wave = threadIdx.x >> 6, lane = threadIdx.x & 63;
  const int row = blockIdx.x * 4 + wave;
  const float4 qv = ((const float4*)(q + (size_t)row * DIM))[lane];
  const float4 tv4 = ((const float4*)(tb + (size_t)row * DIM))[lane];
  const float4 kv = ((const float4*)ksum)[lane];
  float p1 = qv.x * kv.x + qv.y * kv.y + qv.z * kv.z + qv.w * kv.w;
  float p2 = tv4.x * qv.x + tv4.y * qv.y + tv4.z * qv.z + tv4.w * qv.w;
#pragma unroll
  for (int off = 32; off >= 1; off >>= 1) {
    p1 += __shfl_xor(p1, off);
    p2 += __shfl_xor(p2, off);
  }
  if (lane == 0) {
    float tt = (float)tptr[0];
    float sc = 1.f / (16.f * tt);
    float mean = p1 * sc * (1.f / (float)N_ROWS);
    float e2 = p2 * sc * sc * (1.f / (float)N_ROWS);
    float var = fmaxf(e2 - mean * mean, 0.f);
    meanv[row] = mean;
    istdv[row] = 1.f / (sqrtf(var) + 1e-5f);
  }
}

__global__ void prep_kernel(const float* __restrict__ yhat,
                            float* __restrict__ logy) {
  int i = blockIdx.x * 256 + threadIdx.x;
  logy[i] = logf(yhat[i] + 1e-9f);
}

// ---------------------------------------------------------------------------
// Pack (dmask & bmask) into bits (masks are int32 on device)
// ---------------------------------------------------------------------------
__global__ void maskpack_kernel(const int* __restrict__ dmask,
                                const int* __restrict__ bmask,
                                unsigned int* __restrict__ mbits) {
  int gid = blockIdx.x * 256 + threadIdx.x;
  bool v = (dmask[gid] != 0) && (bmask[gid] != 0);
  unsigned long long bal = __ballot(v);
  if ((threadIdx.x & 63) == 0) {
    int w = gid >> 5;
    mbits[w] = (unsigned int)(bal & 0xffffffffu);
    mbits[w + 1] = (unsigned int)(bal >> 32);
  }
}

// ---------------------------------------------------------------------------
// Transpose V f32[4096,256] -> Vt bf16[256,4096]
// ---------------------------------------------------------------------------
__global__ __launch_bounds__(256) void vt_kernel(
    const float* __restrict__ V, unsigned short* __restrict__ Vtb) {
  __shared__ float T[64][65];
  const int n0 = blockIdx.x * 64, d0 = blockIdx.y * 64;
  const int tx = threadIdx.x & 63, ty = threadIdx.x >> 6;
#pragma unroll
  for (int p = 0; p < 16; ++p)
    T[ty + p * 4][tx] = V[(size_t)(n0 + ty + p * 4) * DIM + d0 + tx];
  __syncthreads();
#pragma unroll
  for (int p = 0; p < 16; ++p)
    Vtb[(size_t)(d0 + ty + p * 4) * N_ROWS + n0 + tx] = f2b(T[tx][ty + p * 4]);
}

// ---------------------------------------------------------------------------
// MFMA flash mean-shift attention. grid (64, KSPLIT), block 256 (4 waves).
// Wave handles 16 q-rows; Q in registers (A-frags); K row-major bf16 in
// padded LDS; V pre-transposed bf16 in padded LDS; P via per-wave LDS
// round-trip (C-layout -> A-layout). Online softmax in 16-lane groups.
// ---------------------------------------------------------------------------
__global__ __launch_bounds__(256) void flash_mfma_kernel(
    const unsigned short* __restrict__ Qb, const unsigned short* __restrict__ Kb,
    const unsigned short* __restrict__ Vtb, const float* __restrict__ xyzc,
    const float* __restrict__ logy, const float* __restrict__ meanv,
    const float* __restrict__ istdv, const unsigned int* __restrict__ mbits,
    const int* __restrict__ tptr, const float* __restrict__ bwp,
    const int* __restrict__ usestdp, const int* __restrict__ selfdp,
    unsigned short* __restrict__ paccb, float* __restrict__ pm,
    float* __restrict__ ps, float* __restrict__ pax) {
  __shared__ __align__(16) short Kl[32 * 264];    // rows padded 256->264
  __shared__ __align__(16) short Vtl[256 * 40];   // rows padded 32->40
  __shared__ __align__(16) short Pl[4][16 * 40];  // per-wave P
  __shared__ float xyz_t[32][3];
  __shared__ float sqt[32];
  __shared__ float logyt[32];

  const int tid = threadIdx.x;
  const int wv = tid >> 6, lane = tid & 63;
  const int cl = lane & 15, gq = lane >> 4;
  const int r0 = blockIdx.x * QBLK + wv * 16;
  const int split = blockIdx.y;
  const int colbase = split * COLS_PER_SPLIT;

  const float tv = (float)tptr[0];
  const float scale = 1.f / (16.f * tv);
  const float bw = bwp[0];
  const float inv2bw2 = 1.f / (2.f * bw * bw);
  const int usestd = usestdp[0];
  const float selfd = (float)selfdp[0];

  // Q A-frags: A[row=cl][k = ks*32 + gq*8 + j]
  bf16x8 qa[8];
  {
    const bf16x8* qp = (const bf16x8*)(Qb + (size_t)(r0 + cl) * DIM);
#pragma unroll
    for (int ks = 0; ks < 8; ++ks) qa[ks] = qp[ks * 4 + gq];
  }
  int rowg[4];
  float mrow[4], irow[4], xr[4][3], sqrow[4];
#pragma unroll
  for (int i = 0; i < 4; ++i) {
    rowg[i] = r0 + gq * 4 + i;
    mrow[i] = meanv[rowg[i]];
    irow[i] = istdv[rowg[i]];
    xr[i][0] = xyzc[(size_t)rowg[i] * 3 + 0];
    xr[i][1] = xyzc[(size_t)rowg[i] * 3 + 1];
    xr[i][2] = xyzc[(size_t)rowg[i] * 3 + 2];
    sqrow[i] =
        xr[i][0] * xr[i][0] + xr[i][1] * xr[i][1] + xr[i][2] * xr[i][2];
  }
  float m[4], s[4], ax[4][3];
  f32x4 o[16];
#pragma unroll
  for (int i = 0; i < 4; ++i) {
    m[i] = -INFINITY;
    s[i] = 0.f;
    ax[i][0] = ax[i][1] = ax[i][2] = 0.f;
  }
#pragma unroll
  for (int dt = 0; dt < 16; ++dt) o[dt] = (f32x4){0.f, 0.f, 0.f, 0.f};

  for (int tt = 0; tt < COLS_PER_SPLIT; tt += KBLK) {
    const int t0g = colbase + tt;
    __syncthreads();
    {
      const bf16x8* kg = (const bf16x8*)(Kb + (size_t)t0g * DIM);
#pragma unroll
      for (int p = 0; p < 4; ++p) {
        int cid = tid + p * 256;
        int r = cid >> 5, c = cid & 31;
        *(bf16x8*)&Kl[r * 264 + c * 8] = kg[r * 32 + c];
      }
#pragma unroll
      for (int p = 0; p < 8; ++p) {
        int cid = tid + p * 256;
        int d = cid >> 3, c4 = cid & 7;
        *(bf16x4*)&Vtl[d * 40 + c4 * 4] =
            *(const bf16x4*)&Vtb[(size_t)d * N_ROWS + t0g + c4 * 4];
      }
      if (tid < 32) {
        float a0 = xyzc[(size_t)(t0g + tid) * 3 + 0];
        float a1 = xyzc[(size_t)(t0g + tid) * 3 + 1];
        float a2 = xyzc[(size_t)(t0g + tid) * 3 + 2];
        xyz_t[tid][0] = a0;
        xyz_t[tid][1] = a1;
        xyz_t[tid][2] = a2;
        sqt[tid] = a0 * a0 + a1 * a1 + a2 * a2;
      } else if (tid < 64) {
        logyt[tid - 32] = logy[t0g + tid - 32];
      }
    }
    __syncthreads();

    // QK^T: S[row=gq*4+i][col=ct*16+cl]
    f32x4 st[2];
    st[0] = (f32x4){0.f, 0.f, 0.f, 0.f};
    st[1] = (f32x4){0.f, 0.f, 0.f, 0.f};
#pragma unroll
    for (int ct = 0; ct < 2; ++ct)
#pragma unroll
      for (int ks = 0; ks < 8; ++ks) {
        bf16x8 kf =
            *(const bf16x8*)&Kl[(ct * 16 + cl) * 264 + ks * 32 + gq * 8];
        st[ct] =
            __builtin_amdgcn_mfma_f32_16x16x32_bf16(qa[ks], kf, st[ct], 0, 0, 0);
      }

    unsigned int mw[4];
#pragma unroll
    for (int i = 0; i < 4; ++i)
      mw[i] = mbits[((size_t)rowg[i] << 7) + (t0g >> 5)];

    float corr4[4];
#pragma unroll
    for (int i = 0; i < 4; ++i) {
      float lg0 = 0.f, lg1 = 0.f;
#pragma unroll
      for (int ct = 0; ct < 2; ++ct) {
        int col = ct * 16 + cl;
        float att = st[ct][i] * scale;
        float a = usestd ? (att - mrow[i]) * irow[i] : att;
        float d3 = xr[i][0] * xyz_t[col][0] + xr[i][1] * xyz_t[col][1] +
                   xr[i][2] * xyz_t[col][2];
        float d2 = sqrow[i] + sqt[col] - 2.f * d3;
        d2 = fmaxf(d2, 0.f);
        if (rowg[i] == t0g + col) d2 += selfd;
        float logit = a - d2 * inv2bw2 + logyt[col];
        if (!((mw[i] >> col) & 1u)) logit = -1e9f;
        if (ct == 0) lg0 = logit; else lg1 = logit;
      }
      float tm = fmaxf(lg0, lg1);
      tm = fmaxf(tm, __shfl_xor(tm, 1));
      tm = fmaxf(tm, __shfl_xor(tm, 2));
      tm = fmaxf(tm, __shfl_xor(tm, 4));
      tm = fmaxf(tm, __shfl_xor(tm, 8));
      float nm = fmaxf(m[i], tm);
      float corr = __expf(m[i] - nm);
      float p0 = __expf(lg0 - nm);
      float p1 = __expf(lg1 - nm);
      float es = p0 + p1;
      es += __shfl_xor(es, 1);
      es += __shfl_xor(es, 2);
      es += __shfl_xor(es, 4);
      es += __shfl_xor(es, 8);
      s[i] = s[i] * corr + es;
      m[i] = nm;
      corr4[i] = corr;
      ax[i][0] = ax[i][0] * corr + p0 * xyz_t[cl][0] + p1 * xyz_t[16 + cl][0];
      ax[i][1] = ax[i][1] * corr + p0 * xyz_t[cl][1] + p1 * xyz_t[16 + cl][1];
      ax[i][2] = ax[i][2] * corr + p0 * xyz_t[cl][2] + p1 * xyz_t[16 + cl][2];
      Pl[wv][(gq * 4 + i) * 40 + cl] = (short)f2b(p0);
      Pl[wv][(gq * 4 + i) * 40 + 16 + cl] = (short)f2b(p1);
    }
#pragma unroll
    for (int dt = 0; dt < 16; ++dt) {
      o[dt][0] *= corr4[0];
      o[dt][1] *= corr4[1];
      o[dt][2] *= corr4[2];
      o[dt][3] *= corr4[3];
    }
    // PV: A = P[row=cl][k], B = Vt[d=dt*16+cl][k]
    bf16x8 pf = *(const bf16x8*)&Pl[wv][cl * 40 + gq * 8];
#pragma unroll
    for (int dt = 0; dt < 16; ++dt) {
      bf16x8 vf = *(const bf16x8*)&Vtl[(dt * 16 + cl) * 40 + gq * 8];
      o[dt] = __builtin_amdgcn_mfma_f32_16x16x32_bf16(pf, vf, o[dt], 0, 0, 0);
    }
  }

  // reduce w@xyz partials across the 16-lane group
#pragma unroll
  for (int i = 0; i < 4; ++i)
#pragma unroll
    for (int c = 0; c < 3; ++c) {
      float v = ax[i][c];
      v += __shfl_xor(v, 1);
      v += __shfl_xor(v, 2);
      v += __shfl_xor(v, 4);
      v += __shfl_xor(v, 8);
      ax[i][c] = v;
    }
  if (cl == 0) {
#pragma unroll
    for (int i = 0; i < 4; ++i) {
      size_t idx = (size_t)split * N_ROWS + rowg[i];
      pm[idx] = m[i];
      ps[idx] = s[i];
      pax[idx * 3 + 0] = ax[i][0];
      pax[idx * 3 + 1] = ax[i][1];
      pax[idx * 3 + 2] = ax[i][2];
    }
  }
#pragma unroll
  for (int dt = 0; dt < 16; ++dt)
#pragma unroll
    for (int i = 0; i < 4; ++i)
      paccb[((size_t)split * N_ROWS + rowg[i]) * DIM + dt * 16 + cl] =
          f2b(o[dt][i]);
}

// ---------------------------------------------------------------------------
// Merge KSPLIT partials (exact log-sum-exp combine)
// ---------------------------------------------------------------------------
__global__ __launch_bounds__(256) void merge8_kernel(
    const unsigned short* __restrict__ paccb, const float* __restrict__ pm,
    const float* __restrict__ ps, const float* __restrict__ pax,
    const float* __restrict__ xyzc, const float* __restrict__ betap,
    float* __restrict__ x_att, float* __restrict__ xyz_out) {
  const int wvl = threadIdx.x >> 6, lane = threadIdx.x & 63;
  const int row = blockIdx.x * 4 + wvl;
  float mk[KSPLIT], sk[KSPLIT], fk[KSPLIT];
#pragma unroll
  for (int k = 0; k < KSPLIT; ++k) {
    mk[k] = pm[(size_t)k * N_ROWS + row];
    sk[k] = ps[(size_t)k * N_ROWS + row];
  }
  float mg = mk[0];
#pragma unroll
  for (int k = 1; k < KSPLIT; ++k) mg = fmaxf(mg, mk[k]);
  float den = 0.f;
#pragma unroll
  for (int k = 0; k < KSPLIT; ++k) {
    fk[k] = __expf(mk[k] - mg);
    den += sk[k] * fk[k];
  }
  float inv = 1.f / den;
  float a0 = 0.f, a1 = 0.f, a2 = 0.f, a3 = 0.f;
#pragma unroll
  for (int k = 0; k < KSPLIT; ++k) {
    const unsigned short* p =
        &paccb[((size_t)k * N_ROWS + row) * DIM + lane * 4];
    uint2 u = *(const uint2*)p;
    float b0 = __uint_as_float((u.x & 0xffffu) << 16);
    float b1 = __uint_as_float(u.x & 0xffff0000u);
    float b2 = __uint_as_float((u.y & 0xffffu) << 16);
    float b3 = __uint_as_float(u.y & 0xffff0000u);
    a0 = fmaf(b0, fk[k], a0);
    a1 = fmaf(b1, fk[k], a1);
    a2 = fmaf(b2, fk[k], a2);
    a3 = fmaf(b3, fk[k], a3);
  }
  float4 ov = {a0 * inv, a1 * inv, a2 * inv, a3 * inv};
  ((float4*)(x_att + (size_t)row * DIM))[lane] = ov;
  if (lane < 3) {
    float axs = 0.f;
#pragma unroll
    for (int k = 0; k < KSPLIT; ++k)
      axs += pax[((size_t)k * N_ROWS + row) * 3 + lane] * fk[k];
    float beta = betap[0];
    xyz_out[(size_t)row * 3 + lane] =
        beta * axs * inv + (1.f - beta) * xyzc[(size_t)row * 3 + lane];
  }
}

// ---------------------------------------------------------------------------
// GraphNorm
// ---------------------------------------------------------------------------
__global__ void gn_stats_kernel(const float* __restrict__ X,
                                const int* __restrict__ cums,
                                float* __restrict__ gm,
                                float* __restrict__ gi) {
  int b = blockIdx.x, d = threadIdx.x;
  int r0 = cums[b], r1 = cums[b + 1];
  float s = 0.f, ss = 0.f;
  for (int r = r0; r < r1; ++r) {
    float v = X[(size_t)r * DIM + d];
    s += v;
    ss += v * v;
  }
  float cnt = (float)(r1 - r0);
  float mean = s / fmaxf(cnt, 1.f);
  float var = (ss - cnt * mean * mean) / fmaxf(cnt - 1.f, 1.f);
  gm[b * DIM + d] = mean;
  gi[b * DIM + d] = 1.f / (sqrtf(fmaxf(var, 0.f)) + 1e-5f);
}

__global__ __launch_bounds__(256) void gn_apply_kernel(
    const float* __restrict__ X, const float* __restrict__ gamma,
    const float* __restrict__ betag, const int* __restrict__ cums, int nseg,
    const float* __restrict__ gm, const float* __restrict__ gi,
    float* __restrict__ Xout, float* __restrict__ ofinal) {
  int idx = blockIdx.x * 256 + threadIdx.x;
  int base = idx * 4;
  int row = base >> 8, d0 = base & 255;
  int seg = 0;
  for (int b = 1; b <= nseg; ++b) seg += (row >= cums[b]) ? 1 : 0;
  float4 x = ((const float4*)X)[idx];
  float xs[4] = {x.x, x.y, x.z, x.w};
  const float* gmp = gm + seg * DIM + d0;
  const float* gip = gi + seg * DIM + d0;
  float o[4];
#pragma unroll
  for (int c = 0; c < 4; ++c)
    o[c] = gamma[d0 + c] * (xs[c] - gmp[c]) * gip[c] + betag[d0 + c];
  float4 ov = {o[0], o[1], o[2], o[3]};
  ((float4*)Xout)[idx] = ov;
  if (ofinal) ((float4*)ofinal)[idx] = ov;
}

// ---------------------------------------------------------------------------
extern "C" void kernel_launch(void* const* d_in, const int* in_sizes, int n_in,
                              void* d_out, int out_size, void* d_ws,
                              size_t ws_size, hipStream_t stream) {
  const float* xyz0 = (const float*)d_in[0];
  const float* x0 = (const float*)d_in[1];
  const float* yhat = (const float*)d_in[2];
  const int* dmask = (const int*)d_in[3];
  const int* tptr = (const int*)d_in[4];
  const float* bwp = (const float*)d_in[5];
  const float* betap = (const float*)d_in[6];
  const int* cums = (const int*)d_in[7];
  const int* bmask = (const int*)d_in[8];
  const int* usestdp = (const int*)d_in[9];
  const int* selfdp = (const int*)d_in[10];
  const float* qw = (const float*)d_in[11];
  const float* kw = (const float*)d_in[12];
  const float* vw = (const float*)d_in[13];
  const float* ow = (const float*)d_in[14];
  const float* qbv = (const float*)d_in[15];
  const float* kbv = (const float*)d_in[16];
  const float* vbv = (const float*)d_in[17];
  const float* obv = (const float*)d_in[18];
  const float* gamma = (const float*)d_in[19];
  const float* betag = (const float*)d_in[20];
  float* out = (float*)d_out;
  float* ws = (float*)d_ws;

  const size_t ND = (size_t)N_ROWS * DIM;  // 1,048,576
  float* bq = ws + 0 * ND;
  float* bk = ws + 1 * ND;
  float* bv = ws + 2 * ND;
  float* bt = ws + 3 * ND;  // Q@M for stats (dead during flash)
  float* bh = ws + 4 * ND;  // hosts Qb16+Kb16 during flash, then x_att
  float* bx = ws + 5 * ND;  // layer output
  float* Mp = ws + 6 * ND;          // 2 MB (hosts Vtb during flash)
  float* Mm = Mp + 8 * 65536;       // 65536
  float* kpart = Mm + 65536;        // 16*256
  float* ksum = kpart + 16 * 256;   // 256
  float* meanv = ksum + 256;        // 4096
  float* istdv = meanv + 4096;      // 4096
  float* gm = istdv + 4096;         // 8*256
  float* gi = gm + 8 * 256;         // 8*256
  float* logy = gi + 8 * 256;       // 4096
  float* xyzA = logy + 4096;        // 4096*3
  float* xyzB = xyzA + 3 * N_ROWS;  // 4096*3
  unsigned int* mbits = (unsigned int*)(xyzB + 3 * N_ROWS);  // 4096*128 u32
  float* pm = (float*)(mbits + (size_t)N_ROWS * 128);        // 8*4096
  float* ps = pm + (size_t)KSPLIT * N_ROWS;                  // 8*4096
  float* pax = ps + (size_t)KSPLIT * N_ROWS;                 // 8*4096*3

  unsigned short* paccb = (unsigned short*)ws;  // 16 MB over bq..bt
  unsigned short* Qb16 = (unsigned short*)bh;   // 2 MB
  unsigned short* Kb16 = Qb16 + ND;             // 2 MB
  unsigned short* Vtb = (unsigned short*)Mp;    // 2 MB (exact fit)
  float* x_att = bh;                            // merge output (f32)
  float* bo = bv;                               // O-proj output

  const int nseg = in_sizes[7] - 1;

  prep_kernel<<<16, 256, 0, stream>>>(yhat, logy);
  maskpack_kernel<<<65536, 256, 0, stream>>>(dmask, bmask, mbits);

  for (int l = 0; l < NLAYER; ++l) {
    const float* xin = (l == 0) ? x0 : bx;
    const float* xyz_in = (l == 0) ? xyz0 : ((l & 1) ? xyzB : xyzA);
    float* xyz_o = (l & 1) ? xyzA : xyzB;
    const float* Wq = qw + (size_t)l * DIM * DIM;
    const float* Wk = kw + (size_t)l * DIM * DIM;
    const float* Wv = vw + (size_t)l * DIM * DIM;
    const float* Wo = ow + (size_t)l * DIM * DIM;

    gemm_qkv_kernel<<<dim3(64, 4, 3), 256, 0, stream>>>(
        xin, Wq, Wk, Wv, qbv + l * DIM, kbv + l * DIM, vbv + l * DIM, bq, bk,
        bv, Qb16, Kb16);
    ksum_part_kernel<<<16, 256, 0, stream>>>(bk, kpart);
    ksum_red_kernel<<<1, 256, 0, stream>>>(kpart, ksum);
    mpart_kernel<<<dim3(4, 4, 8), 256, 0, stream>>>(bk, Mp);
    mreduce_kernel<<<256, 256, 0, stream>>>(Mp, Mm);
    gemm_nt_kernel<<<dim3(64, 4), 256, 0, stream>>>(bq, Mm, nullptr, nullptr,
                                                    bt);
    stats_kernel<<<1024, 256, 0, stream>>>(bq, bt, ksum, tptr, meanv, istdv);
    vt_kernel<<<dim3(64, 4), 256, 0, stream>>>(bv, Vtb);  // Mp now dead
    flash_mfma_kernel<<<dim3(64, KSPLIT), 256, 0, stream>>>(
        Qb16, Kb16, Vtb, xyz_in, logy, meanv, istdv, mbits, tptr, bwp, usestdp,
        selfdp, paccb, pm, ps, pax);
    merge8_kernel<<<1024, 256, 0, stream>>>(paccb, pm, ps, pax, xyz_in, betap,
                                            x_att, xyz_o);
    gemm_nt_kernel<<<dim3(64, 4), 256, 0, stream>>>(x_att, Wo, obv + l * DIM,
                                                    xin, bo);
    gn_stats_kernel<<<nseg, 256, 0, stream>>>(bo, cums, gm, gi);
    gn_apply_kernel<<<1024, 256, 0, stream>>>(
        bo, gamma + (size_t)l * DIM, betag + (size_t)l * DIM, cums, nseg, gm,
        gi, bx, (l == NLAYER - 1) ? out : nullptr);
  }
}

// Round 6
// 1079.706 us; speedup vs baseline: 4.9023x; 1.4377x over previous
//
#include <hip/hip_runtime.h>
#include <hip/hip_bf16.h>
#include <math.h>

#define N_ROWS 4096
#define DIM    256
#define NLAYER 4
#define KSPLIT 8
#define COLS_PER_SPLIT (N_ROWS / KSPLIT)
#define QBLK 64
#define KBLK 32
#define GN_CHUNKS 16

typedef __attribute__((ext_vector_type(8))) short bf16x8;
typedef __attribute__((ext_vector_type(4))) short bf16x4;
typedef __attribute__((ext_vector_type(4))) float f32x4;

__device__ __forceinline__ unsigned short f2b(float f) {
  unsigned int u = __float_as_uint(f);
  unsigned int r = (u + 0x7fffu + ((u >> 16) & 1u)) >> 16;
  return (unsigned short)r;
}

// ---------------------------------------------------------------------------
// Generic NT GEMM: C[M,256] = A[M,256] @ B[256,256]^T (+bias)(+res)
// ---------------------------------------------------------------------------
__global__ __launch_bounds__(256) void gemm_nt_kernel(
    const float* __restrict__ A, const float* __restrict__ Bm,
    const float* __restrict__ bias, const float* __restrict__ res,
    float* __restrict__ C) {
  __shared__ float As[16][65];
  __shared__ float Bs[16][65];
  const int m0 = blockIdx.x * 64, n0 = blockIdx.y * 64;
  const int tid = threadIdx.x;
  const int tx = tid & 15, ty = tid >> 4;
  float acc[4][4] = {};
  for (int k0 = 0; k0 < DIM; k0 += 16) {
    __syncthreads();
#pragma unroll
    for (int p = 0; p < 4; ++p) {
      int row = ty + p * 16;
      As[tx][row] = A[(size_t)(m0 + row) * DIM + k0 + tx];
      Bs[tx][row] = Bm[(size_t)(n0 + row) * DIM + k0 + tx];
    }
    __syncthreads();
#pragma unroll
    for (int kk = 0; kk < 16; ++kk) {
      float a[4], b[4];
#pragma unroll
      for (int r = 0; r < 4; ++r) a[r] = As[kk][ty + r * 16];
#pragma unroll
      for (int c = 0; c < 4; ++c) b[c] = Bs[kk][tx + c * 16];
#pragma unroll
      for (int r = 0; r < 4; ++r)
#pragma unroll
        for (int c = 0; c < 4; ++c) acc[r][c] = fmaf(a[r], b[c], acc[r][c]);
    }
  }
#pragma unroll
  for (int r = 0; r < 4; ++r) {
    int m = m0 + ty + r * 16;
#pragma unroll
    for (int c = 0; c < 4; ++c) {
      int n = n0 + tx + c * 16;
      float vv = acc[r][c];
      if (bias) vv += bias[n];
      if (res) vv += res[(size_t)m * DIM + n];
      C[(size_t)m * DIM + n] = vv;
    }
  }
}

// Fused QKV with bf16 side-outputs for Q and K
__global__ __launch_bounds__(256) void gemm_qkv_kernel(
    const float* __restrict__ A, const float* __restrict__ W0,
    const float* __restrict__ W1, const float* __restrict__ W2,
    const float* __restrict__ b0, const float* __restrict__ b1,
    const float* __restrict__ b2, float* __restrict__ C0,
    float* __restrict__ C1, float* __restrict__ C2,
    unsigned short* __restrict__ Qb16, unsigned short* __restrict__ Kb16) {
  const float* Bm = (blockIdx.z == 0) ? W0 : (blockIdx.z == 1) ? W1 : W2;
  const float* bias = (blockIdx.z == 0) ? b0 : (blockIdx.z == 1) ? b1 : b2;
  float* C = (blockIdx.z == 0) ? C0 : (blockIdx.z == 1) ? C1 : C2;
  unsigned short* Cb =
      (blockIdx.z == 0) ? Qb16 : (blockIdx.z == 1) ? Kb16 : nullptr;
  __shared__ float As[16][65];
  __shared__ float Bs[16][65];
  const int m0 = blockIdx.x * 64, n0 = blockIdx.y * 64;
  const int tid = threadIdx.x;
  const int tx = tid & 15, ty = tid >> 4;
  float acc[4][4] = {};
  for (int k0 = 0; k0 < DIM; k0 += 16) {
    __syncthreads();
#pragma unroll
    for (int p = 0; p < 4; ++p) {
      int row = ty + p * 16;
      As[tx][row] = A[(size_t)(m0 + row) * DIM + k0 + tx];
      Bs[tx][row] = Bm[(size_t)(n0 + row) * DIM + k0 + tx];
    }
    __syncthreads();
#pragma unroll
    for (int kk = 0; kk < 16; ++kk) {
      float a[4], b[4];
#pragma unroll
      for (int r = 0; r < 4; ++r) a[r] = As[kk][ty + r * 16];
#pragma unroll
      for (int c = 0; c < 4; ++c) b[c] = Bs[kk][tx + c * 16];
#pragma unroll
      for (int r = 0; r < 4; ++r)
#pragma unroll
        for (int c = 0; c < 4; ++c) acc[r][c] = fmaf(a[r], b[c], acc[r][c]);
    }
  }
#pragma unroll
  for (int r = 0; r < 4; ++r) {
    int m = m0 + ty + r * 16;
#pragma unroll
    for (int c = 0; c < 4; ++c) {
      int n = n0 + tx + c * 16;
      float vv = acc[r][c] + bias[n];
      C[(size_t)m * DIM + n] = vv;
      if (Cb) Cb[(size_t)m * DIM + n] = f2b(vv);
    }
  }
}

// ---------------------------------------------------------------------------
// ksum = column sum of K (2-stage, 64-way)
// ---------------------------------------------------------------------------
__global__ void ksum_part_kernel(const float* __restrict__ K,
                                 float* __restrict__ kpart) {
  int d = threadIdx.x, b = blockIdx.x;
  float s = 0.f;
  int base = b * 64;
  for (int n = 0; n < 64; ++n) s += K[(size_t)(base + n) * DIM + d];
  kpart[b * DIM + d] = s;
}
__global__ void ksum_red_kernel(const float* __restrict__ kpart,
                                float* __restrict__ ksum) {
  int d = threadIdx.x;
  float s = 0.f;
  for (int b = 0; b < 64; ++b) s += kpart[b * DIM + d];
  ksum[d] = s;
}

// ---------------------------------------------------------------------------
// Mpart[z] = K[z*512:(z+1)*512,:]^T @ K[...] ; grid(4,4,8)
// ---------------------------------------------------------------------------
__global__ __launch_bounds__(256) void mpart_kernel(const float* __restrict__ K,
                                                    float* __restrict__ Mpart) {
  __shared__ float Ka[32][65];
  __shared__ float Kb[32][65];
  const int a0 = blockIdx.x * 64, b0 = blockIdx.y * 64, z = blockIdx.z;
  const int tid = threadIdx.x;
  const int tx = tid & 15, ty = tid >> 4;
  float acc[4][4] = {};
  for (int nb = 0; nb < 512; nb += 32) {
    __syncthreads();
#pragma unroll
    for (int i = 0; i < 8; ++i) {
      int e = tid + i * 256;
      int nr = e >> 6, cc = e & 63;
      size_t rowoff = (size_t)(z * 512 + nb + nr) * DIM;
      Ka[nr][cc] = K[rowoff + a0 + cc];
      Kb[nr][cc] = K[rowoff + b0 + cc];
    }
    __syncthreads();
#pragma unroll
    for (int kk = 0; kk < 32; ++kk) {
      float a[4], b[4];
#pragma unroll
      for (int r = 0; r < 4; ++r) a[r] = Ka[kk][ty + r * 16];
#pragma unroll
      for (int c = 0; c < 4; ++c) b[c] = Kb[kk][tx + c * 16];
#pragma unroll
      for (int r = 0; r < 4; ++r)
#pragma unroll
        for (int c = 0; c < 4; ++c) acc[r][c] = fmaf(a[r], b[c], acc[r][c]);
    }
  }
#pragma unroll
  for (int r = 0; r < 4; ++r)
#pragma unroll
    for (int c = 0; c < 4; ++c)
      Mpart[((size_t)z << 16) + (size_t)(a0 + ty + r * 16) * DIM + b0 + tx +
            c * 16] = acc[r][c];
}
__global__ void mreduce_kernel(const float* __restrict__ Mp,
                               float* __restrict__ Mm) {
  int e = blockIdx.x * 256 + threadIdx.x;
  float s = 0.f;
#pragma unroll
  for (int z = 0; z < 8; ++z) s += Mp[(size_t)z * 65536 + e];
  Mm[e] = s;
}

// ---------------------------------------------------------------------------
// Per-row att mean / inv-std
// ---------------------------------------------------------------------------
__global__ __launch_bounds__(256) void stats_kernel(
    const float* __restrict__ q, const float* __restrict__ tb,
    const float* __restrict__ ksum, const int* __restrict__ tptr,
    float* __restrict__ meanv, float* __restrict__ istdv) {
  const int wave = threadIdx.x >> 6, lane = threadIdx.x & 63;
  const int row = blockIdx.x * 4 + wave;
  const float4 qv = ((const float4*)(q + (size_t)row * DIM))[lane];
  const float4 tv4 = ((const float4*)(tb + (size_t)row * DIM))[lane];
  const float4 kv = ((const float4*)ksum)[lane];
  float p1 = qv.x * kv.x + qv.y * kv.y + qv.z * kv.z + qv.w * kv.w;
  float p2 = tv4.x * qv.x + tv4.y * qv.y + tv4.z * qv.z + tv4.w * qv.w;
#pragma unroll
  for (int off = 32; off >= 1; off >>= 1) {
    p1 += __shfl_xor(p1, off);
    p2 += __shfl_xor(p2, off);
  }
  if (lane == 0) {
    float tt = (float)tptr[0];
    float sc = 1.f / (16.f * tt);
    float mean = p1 * sc * (1.f / (float)N_ROWS);
    float e2 = p2 * sc * sc * (1.f / (float)N_ROWS);
    float var = fmaxf(e2 - mean * mean, 0.f);
    meanv[row] = mean;
    istdv[row] = 1.f / (sqrtf(var) + 1e-5f);
  }
}

__global__ void prep_kernel(const float* __restrict__ yhat,
                            float* __restrict__ logy) {
  int i = blockIdx.x * 256 + threadIdx.x;
  logy[i] = logf(yhat[i] + 1e-9f);
}

// ---------------------------------------------------------------------------
// Pack (dmask & bmask) into bits (masks are int32 on device)
// ---------------------------------------------------------------------------
__global__ void maskpack_kernel(const int* __restrict__ dmask,
                                const int* __restrict__ bmask,
                                unsigned int* __restrict__ mbits) {
  int gid = blockIdx.x * 256 + threadIdx.x;
  bool v = (dmask[gid] != 0) && (bmask[gid] != 0);
  unsigned long long bal = __ballot(v);
  if ((threadIdx.x & 63) == 0) {
    int w = gid >> 5;
    mbits[w] = (unsigned int)(bal & 0xffffffffu);
    mbits[w + 1] = (unsigned int)(bal >> 32);
  }
}

// ---------------------------------------------------------------------------
// Transpose V f32[4096,256] -> Vt bf16[256,4096]
// ---------------------------------------------------------------------------
__global__ __launch_bounds__(256) void vt_kernel(
    const float* __restrict__ V, unsigned short* __restrict__ Vtb) {
  __shared__ float T[64][65];
  const int n0 = blockIdx.x * 64, d0 = blockIdx.y * 64;
  const int tx = threadIdx.x & 63, ty = threadIdx.x >> 6;
#pragma unroll
  for (int p = 0; p < 16; ++p)
    T[ty + p * 4][tx] = V[(size_t)(n0 + ty + p * 4) * DIM + d0 + tx];
  __syncthreads();
#pragma unroll
  for (int p = 0; p < 16; ++p)
    Vtb[(size_t)(d0 + ty + p * 4) * N_ROWS + n0 + tx] = f2b(T[tx][ty + p * 4]);
}

// ---------------------------------------------------------------------------
// MFMA flash mean-shift attention. grid (64, KSPLIT), block 256 (4 waves).
// ---------------------------------------------------------------------------
__global__ __launch_bounds__(256) void flash_mfma_kernel(
    const unsigned short* __restrict__ Qb, const unsigned short* __restrict__ Kb,
    const unsigned short* __restrict__ Vtb, const float* __restrict__ xyzc,
    const float* __restrict__ logy, const float* __restrict__ meanv,
    const float* __restrict__ istdv, const unsigned int* __restrict__ mbits,
    const int* __restrict__ tptr, const float* __restrict__ bwp,
    const int* __restrict__ usestdp, const int* __restrict__ selfdp,
    unsigned short* __restrict__ paccb, float* __restrict__ pm,
    float* __restrict__ ps, float* __restrict__ pax) {
  __shared__ __align__(16) short Kl[32 * 264];    // rows padded 256->264
  __shared__ __align__(16) short Vtl[256 * 40];   // rows padded 32->40
  __shared__ __align__(16) short Pl[4][16 * 40];  // per-wave P
  __shared__ float xyz_t[32][3];
  __shared__ float sqt[32];
  __shared__ float logyt[32];

  const int tid = threadIdx.x;
  const int wv = tid >> 6, lane = tid & 63;
  const int cl = lane & 15, gq = lane >> 4;
  const int r0 = blockIdx.x * QBLK + wv * 16;
  const int split = blockIdx.y;
  const int colbase = split * COLS_PER_SPLIT;

  const float tv = (float)tptr[0];
  const float scale = 1.f / (16.f * tv);
  const float bw = bwp[0];
  const float inv2bw2 = 1.f / (2.f * bw * bw);
  const int usestd = usestdp[0];
  const float selfd = (float)selfdp[0];

  bf16x8 qa[8];
  {
    const bf16x8* qp = (const bf16x8*)(Qb + (size_t)(r0 + cl) * DIM);
#pragma unroll
    for (int ks = 0; ks < 8; ++ks) qa[ks] = qp[ks * 4 + gq];
  }
  int rowg[4];
  float mrow[4], irow[4], xr[4][3], sqrow[4];
#pragma unroll
  for (int i = 0; i < 4; ++i) {
    rowg[i] = r0 + gq * 4 + i;
    mrow[i] = meanv[rowg[i]];
    irow[i] = istdv[rowg[i]];
    xr[i][0] = xyzc[(size_t)rowg[i] * 3 + 0];
    xr[i][1] = xyzc[(size_t)rowg[i] * 3 + 1];
    xr[i][2] = xyzc[(size_t)rowg[i] * 3 + 2];
    sqrow[i] =
        xr[i][0] * xr[i][0] + xr[i][1] * xr[i][1] + xr[i][2] * xr[i][2];
  }
  float m[4], s[4], ax[4][3];
  f32x4 o[16];
#pragma unroll
  for (int i = 0; i < 4; ++i) {
    m[i] = -INFINITY;
    s[i] = 0.f;
    ax[i][0] = ax[i][1] = ax[i][2] = 0.f;
  }
#pragma unroll
  for (int dt = 0; dt < 16; ++dt) o[dt] = (f32x4){0.f, 0.f, 0.f, 0.f};

  for (int tt = 0; tt < COLS_PER_SPLIT; tt += KBLK) {
    const int t0g = colbase + tt;
    __syncthreads();
    {
      const bf16x8* kg = (const bf16x8*)(Kb + (size_t)t0g * DIM);
#pragma unroll
      for (int p = 0; p < 4; ++p) {
        int cid = tid + p * 256;
        int r = cid >> 5, c = cid & 31;
        *(bf16x8*)&Kl[r * 264 + c * 8] = kg[r * 32 + c];
      }
#pragma unroll
      for (int p = 0; p < 8; ++p) {
        int cid = tid + p * 256;
        int d = cid >> 3, c4 = cid & 7;
        *(bf16x4*)&Vtl[d * 40 + c4 * 4] =
            *(const bf16x4*)&Vtb[(size_t)d * N_ROWS + t0g + c4 * 4];
      }
      if (tid < 32) {
        float a0 = xyzc[(size_t)(t0g + tid) * 3 + 0];
        float a1 = xyzc[(size_t)(t0g + tid) * 3 + 1];
        float a2 = xyzc[(size_t)(t0g + tid) * 3 + 2];
        xyz_t[tid][0] = a0;
        xyz_t[tid][1] = a1;
        xyz_t[tid][2] = a2;
        sqt[tid] = a0 * a0 + a1 * a1 + a2 * a2;
      } else if (tid < 64) {
        logyt[tid - 32] = logy[t0g + tid - 32];
      }
    }
    __syncthreads();

    f32x4 st[2];
    st[0] = (f32x4){0.f, 0.f, 0.f, 0.f};
    st[1] = (f32x4){0.f, 0.f, 0.f, 0.f};
#pragma unroll
    for (int ct = 0; ct < 2; ++ct)
#pragma unroll
      for (int ks = 0; ks < 8; ++ks) {
        bf16x8 kf =
            *(const bf16x8*)&Kl[(ct * 16 + cl) * 264 + ks * 32 + gq * 8];
        st[ct] =
            __builtin_amdgcn_mfma_f32_16x16x32_bf16(qa[ks], kf, st[ct], 0, 0, 0);
      }

    unsigned int mw[4];
#pragma unroll
    for (int i = 0; i < 4; ++i)
      mw[i] = mbits[((size_t)rowg[i] << 7) + (t0g >> 5)];

    float corr4[4];
#pragma unroll
    for (int i = 0; i < 4; ++i) {
      float lg0 = 0.f, lg1 = 0.f;
#pragma unroll
      for (int ct = 0; ct < 2; ++ct) {
        int col = ct * 16 + cl;
        float att = st[ct][i] * scale;
        float a = usestd ? (att - mrow[i]) * irow[i] : att;
        float d3 = xr[i][0] * xyz_t[col][0] + xr[i][1] * xyz_t[col][1] +
                   xr[i][2] * xyz_t[col][2];
        float d2 = sqrow[i] + sqt[col] - 2.f * d3;
        d2 = fmaxf(d2, 0.f);
        if (rowg[i] == t0g + col) d2 += selfd;
        float logit = a - d2 * inv2bw2 + logyt[col];
        if (!((mw[i] >> col) & 1u)) logit = -1e9f;
        if (ct == 0) lg0 = logit; else lg1 = logit;
      }
      float tm = fmaxf(lg0, lg1);
      tm = fmaxf(tm, __shfl_xor(tm, 1));
      tm = fmaxf(tm, __shfl_xor(tm, 2));
      tm = fmaxf(tm, __shfl_xor(tm, 4));
      tm = fmaxf(tm, __shfl_xor(tm, 8));
      float nm = fmaxf(m[i], tm);
      float corr = __expf(m[i] - nm);
      float p0 = __expf(lg0 - nm);
      float p1 = __expf(lg1 - nm);
      float es = p0 + p1;
      es += __shfl_xor(es, 1);
      es += __shfl_xor(es, 2);
      es += __shfl_xor(es, 4);
      es += __shfl_xor(es, 8);
      s[i] = s[i] * corr + es;
      m[i] = nm;
      corr4[i] = corr;
      ax[i][0] = ax[i][0] * corr + p0 * xyz_t[cl][0] + p1 * xyz_t[16 + cl][0];
      ax[i][1] = ax[i][1] * corr + p0 * xyz_t[cl][1] + p1 * xyz_t[16 + cl][1];
      ax[i][2] = ax[i][2] * corr + p0 * xyz_t[cl][2] + p1 * xyz_t[16 + cl][2];
      Pl[wv][(gq * 4 + i) * 40 + cl] = (short)f2b(p0);
      Pl[wv][(gq * 4 + i) * 40 + 16 + cl] = (short)f2b(p1);
    }
#pragma unroll
    for (int dt = 0; dt < 16; ++dt) {
      o[dt][0] *= corr4[0];
      o[dt][1] *= corr4[1];
      o[dt][2] *= corr4[2];
      o[dt][3] *= corr4[3];
    }
    bf16x8 pf = *(const bf16x8*)&Pl[wv][cl * 40 + gq * 8];
#pragma unroll
    for (int dt = 0; dt < 16; ++dt) {
      bf16x8 vf = *(const bf16x8*)&Vtl[(dt * 16 + cl) * 40 + gq * 8];
      o[dt] = __builtin_amdgcn_mfma_f32_16x16x32_bf16(pf, vf, o[dt], 0, 0, 0);
    }
  }

#pragma unroll
  for (int i = 0; i < 4; ++i)
#pragma unroll
    for (int c = 0; c < 3; ++c) {
      float v = ax[i][c];
      v += __shfl_xor(v, 1);
      v += __shfl_xor(v, 2);
      v += __shfl_xor(v, 4);
      v += __shfl_xor(v, 8);
      ax[i][c] = v;
    }
  if (cl == 0) {
#pragma unroll
    for (int i = 0; i < 4; ++i) {
      size_t idx = (size_t)split * N_ROWS + rowg[i];
      pm[idx] = m[i];
      ps[idx] = s[i];
      pax[idx * 3 + 0] = ax[i][0];
      pax[idx * 3 + 1] = ax[i][1];
      pax[idx * 3 + 2] = ax[i][2];
    }
  }
#pragma unroll
  for (int dt = 0; dt < 16; ++dt)
#pragma unroll
    for (int i = 0; i < 4; ++i)
      paccb[((size_t)split * N_ROWS + rowg[i]) * DIM + dt * 16 + cl] =
          f2b(o[dt][i]);
}

// ---------------------------------------------------------------------------
// Merge KSPLIT partials (exact log-sum-exp combine)
// ---------------------------------------------------------------------------
__global__ __launch_bounds__(256) void merge8_kernel(
    const unsigned short* __restrict__ paccb, const float* __restrict__ pm,
    const float* __restrict__ ps, const float* __restrict__ pax,
    const float* __restrict__ xyzc, const float* __restrict__ betap,
    float* __restrict__ x_att, float* __restrict__ xyz_out) {
  const int wvl = threadIdx.x >> 6, lane = threadIdx.x & 63;
  const int row = blockIdx.x * 4 + wvl;
  float mk[KSPLIT], sk[KSPLIT], fk[KSPLIT];
#pragma unroll
  for (int k = 0; k < KSPLIT; ++k) {
    mk[k] = pm[(size_t)k * N_ROWS + row];
    sk[k] = ps[(size_t)k * N_ROWS + row];
  }
  float mg = mk[0];
#pragma unroll
  for (int k = 1; k < KSPLIT; ++k) mg = fmaxf(mg, mk[k]);
  float den = 0.f;
#pragma unroll
  for (int k = 0; k < KSPLIT; ++k) {
    fk[k] = __expf(mk[k] - mg);
    den += sk[k] * fk[k];
  }
  float inv = 1.f / den;
  float a0 = 0.f, a1 = 0.f, a2 = 0.f, a3 = 0.f;
#pragma unroll
  for (int k = 0; k < KSPLIT; ++k) {
    const unsigned short* p =
        &paccb[((size_t)k * N_ROWS + row) * DIM + lane * 4];
    uint2 u = *(const uint2*)p;
    float b0 = __uint_as_float((u.x & 0xffffu) << 16);
    float b1 = __uint_as_float(u.x & 0xffff0000u);
    float b2 = __uint_as_float((u.y & 0xffffu) << 16);
    float b3 = __uint_as_float(u.y & 0xffff0000u);
    a0 = fmaf(b0, fk[k], a0);
    a1 = fmaf(b1, fk[k], a1);
    a2 = fmaf(b2, fk[k], a2);
    a3 = fmaf(b3, fk[k], a3);
  }
  float4 ov = {a0 * inv, a1 * inv, a2 * inv, a3 * inv};
  ((float4*)(x_att + (size_t)row * DIM))[lane] = ov;
  if (lane < 3) {
    float axs = 0.f;
#pragma unroll
    for (int k = 0; k < KSPLIT; ++k)
      axs += pax[((size_t)k * N_ROWS + row) * 3 + lane] * fk[k];
    float beta = betap[0];
    xyz_out[(size_t)row * 3 + lane] =
        beta * axs * inv + (1.f - beta) * xyzc[(size_t)row * 3 + lane];
  }
}

// ---------------------------------------------------------------------------
// GraphNorm: two-stage parallel stats, then apply
// ---------------------------------------------------------------------------
__global__ __launch_bounds__(256) void gn_part_kernel(
    const float* __restrict__ X, const int* __restrict__ cums,
    float* __restrict__ gpart) {
  const int seg = blockIdx.x, chunk = blockIdx.y, d = threadIdx.x;
  const int r0 = cums[seg], r1 = cums[seg + 1];
  const int cnt = r1 - r0;
  const int per = (cnt + GN_CHUNKS - 1) / GN_CHUNKS;
  const int a = r0 + chunk * per;
  const int b = min(a + per, r1);
  float s = 0.f, ss = 0.f;
  for (int r = a; r < b; ++r) {
    float v = X[(size_t)r * DIM + d];
    s += v;
    ss += v * v;
  }
  gpart[(((size_t)seg * GN_CHUNKS + chunk) * 2 + 0) * DIM + d] = s;
  gpart[(((size_t)seg * GN_CHUNKS + chunk) * 2 + 1) * DIM + d] = ss;
}

__global__ void gn_red_kernel(const float* __restrict__ gpart,
                              const int* __restrict__ cums,
                              float* __restrict__ gm, float* __restrict__ gi) {
  const int seg = blockIdx.x, d = threadIdx.x;
  float s = 0.f, ss = 0.f;
#pragma unroll
  for (int c = 0; c < GN_CHUNKS; ++c) {
    s += gpart[(((size_t)seg * GN_CHUNKS + c) * 2 + 0) * DIM + d];
    ss += gpart[(((size_t)seg * GN_CHUNKS + c) * 2 + 1) * DIM + d];
  }
  float cnt = (float)(cums[seg + 1] - cums[seg]);
  float mean = s / fmaxf(cnt, 1.f);
  float var = (ss - cnt * mean * mean) / fmaxf(cnt - 1.f, 1.f);
  gm[seg * DIM + d] = mean;
  gi[seg * DIM + d] = 1.f / (sqrtf(fmaxf(var, 0.f)) + 1e-5f);
}

__global__ __launch_bounds__(256) void gn_apply_kernel(
    const float* __restrict__ X, const float* __restrict__ gamma,
    const float* __restrict__ betag, const int* __restrict__ cums, int nseg,
    const float* __restrict__ gm, const float* __restrict__ gi,
    float* __restrict__ Xout, float* __restrict__ ofinal) {
  int idx = blockIdx.x * 256 + threadIdx.x;
  int base = idx * 4;
  int row = base >> 8, d0 = base & 255;
  int seg = 0;
  for (int b = 1; b <= nseg; ++b) seg += (row >= cums[b]) ? 1 : 0;
  float4 x = ((const float4*)X)[idx];
  float xs[4] = {x.x, x.y, x.z, x.w};
  const float* gmp = gm + seg * DIM + d0;
  const float* gip = gi + seg * DIM + d0;
  float o[4];
#pragma unroll
  for (int c = 0; c < 4; ++c)
    o[c] = gamma[d0 + c] * (xs[c] - gmp[c]) * gip[c] + betag[d0 + c];
  float4 ov = {o[0], o[1], o[2], o[3]};
  ((float4*)Xout)[idx] = ov;
  if (ofinal) ((float4*)ofinal)[idx] = ov;
}

// ---------------------------------------------------------------------------
extern "C" void kernel_launch(void* const* d_in, const int* in_sizes, int n_in,
                              void* d_out, int out_size, void* d_ws,
                              size_t ws_size, hipStream_t stream) {
  const float* xyz0 = (const float*)d_in[0];
  const float* x0 = (const float*)d_in[1];
  const float* yhat = (const float*)d_in[2];
  const int* dmask = (const int*)d_in[3];
  const int* tptr = (const int*)d_in[4];
  const float* bwp = (const float*)d_in[5];
  const float* betap = (const float*)d_in[6];
  const int* cums = (const int*)d_in[7];
  const int* bmask = (const int*)d_in[8];
  const int* usestdp = (const int*)d_in[9];
  const int* selfdp = (const int*)d_in[10];
  const float* qw = (const float*)d_in[11];
  const float* kw = (const float*)d_in[12];
  const float* vw = (const float*)d_in[13];
  const float* ow = (const float*)d_in[14];
  const float* qbv = (const float*)d_in[15];
  const float* kbv = (const float*)d_in[16];
  const float* vbv = (const float*)d_in[17];
  const float* obv = (const float*)d_in[18];
  const float* gamma = (const float*)d_in[19];
  const float* betag = (const float*)d_in[20];
  float* out = (float*)d_out;
  float* ws = (float*)d_ws;

  const size_t ND = (size_t)N_ROWS * DIM;  // 1,048,576
  float* bq = ws + 0 * ND;
  float* bk = ws + 1 * ND;
  float* bv = ws + 2 * ND;
  float* bt = ws + 3 * ND;  // Q@M for stats (dead during flash)
  float* bh = ws + 4 * ND;  // hosts Qb16+Kb16 during flash, then x_att
  float* bx = ws + 5 * ND;  // layer output
  float* Mp = ws + 6 * ND;          // 2 MB (hosts Vtb during flash)
  float* Mm = Mp + 8 * 65536;       // 65536
  float* kpart = Mm + 65536;        // 64*256
  float* ksum = kpart + 64 * 256;   // 256
  float* meanv = ksum + 256;        // 4096
  float* istdv = meanv + 4096;      // 4096
  float* gm = istdv + 4096;         // 8*256
  float* gi = gm + 8 * 256;         // 8*256
  float* logy = gi + 8 * 256;       // 4096
  float* xyzA = logy + 4096;        // 4096*3
  float* xyzB = xyzA + 3 * N_ROWS;  // 4096*3
  unsigned int* mbits = (unsigned int*)(xyzB + 3 * N_ROWS);  // 4096*128 u32
  float* pm = (float*)(mbits + (size_t)N_ROWS * 128);        // 8*4096
  float* ps = pm + (size_t)KSPLIT * N_ROWS;                  // 8*4096
  float* pax = ps + (size_t)KSPLIT * N_ROWS;                 // 8*4096*3
  float* gpart = pax + (size_t)KSPLIT * N_ROWS * 3;          // 8*16*2*256

  unsigned short* paccb = (unsigned short*)ws;  // 16 MB over bq..bt
  unsigned short* Qb16 = (unsigned short*)bh;   // 2 MB
  unsigned short* Kb16 = Qb16 + ND;             // 2 MB
  unsigned short* Vtb = (unsigned short*)Mp;    // 2 MB (exact fit)
  float* x_att = bh;                            // merge output (f32)
  float* bo = bv;                               // O-proj output

  const int nseg = in_sizes[7] - 1;

  prep_kernel<<<16, 256, 0, stream>>>(yhat, logy);
  maskpack_kernel<<<65536, 256, 0, stream>>>(dmask, bmask, mbits);

  for (int l = 0; l < NLAYER; ++l) {
    const float* xin = (l == 0) ? x0 : bx;
    const float* xyz_in = (l == 0) ? xyz0 : ((l & 1) ? xyzB : xyzA);
    float* xyz_o = (l & 1) ? xyzA : xyzB;
    const float* Wq = qw + (size_t)l * DIM * DIM;
    const float* Wk = kw + (size_t)l * DIM * DIM;
    const float* Wv = vw + (size_t)l * DIM * DIM;
    const float* Wo = ow + (size_t)l * DIM * DIM;

    gemm_qkv_kernel<<<dim3(64, 4, 3), 256, 0, stream>>>(
        xin, Wq, Wk, Wv, qbv + l * DIM, kbv + l * DIM, vbv + l * DIM, bq, bk,
        bv, Qb16, Kb16);
    ksum_part_kernel<<<64, 256, 0, stream>>>(bk, kpart);
    ksum_red_kernel<<<1, 256, 0, stream>>>(kpart, ksum);
    mpart_kernel<<<dim3(4, 4, 8), 256, 0, stream>>>(bk, Mp);
    mreduce_kernel<<<256, 256, 0, stream>>>(Mp, Mm);
    gemm_nt_kernel<<<dim3(64, 4), 256, 0, stream>>>(bq, Mm, nullptr, nullptr,
                                                    bt);
    stats_kernel<<<1024, 256, 0, stream>>>(bq, bt, ksum, tptr, meanv, istdv);
    vt_kernel<<<dim3(64, 4), 256, 0, stream>>>(bv, Vtb);  // Mp now dead
    flash_mfma_kernel<<<dim3(64, KSPLIT), 256, 0, stream>>>(
        Qb16, Kb16, Vtb, xyz_in, logy, meanv, istdv, mbits, tptr, bwp, usestdp,
        selfdp, paccb, pm, ps, pax);
    merge8_kernel<<<1024, 256, 0, stream>>>(paccb, pm, ps, pax, xyz_in, betap,
                                            x_att, xyz_o);
    gemm_nt_kernel<<<dim3(64, 4), 256, 0, stream>>>(x_att, Wo, obv + l * DIM,
                                                    xin, bo);
    gn_part_kernel<<<dim3(nseg, GN_CHUNKS), 256, 0, stream>>>(bo, cums, gpart);
    gn_red_kernel<<<nseg, 256, 0, stream>>>(gpart, cums, gm, gi);
    gn_apply_kernel<<<1024, 256, 0, stream>>>(
        bo, gamma + (size_t)l * DIM, betag + (size_t)l * DIM, cums, nseg, gm,
        gi, bx, (l == NLAYER - 1) ? out : nullptr);
  }
}

// Round 7
// 867.790 us; speedup vs baseline: 6.0995x; 1.2442x over previous
//
#include <hip/hip_runtime.h>
#include <hip/hip_bf16.h>
#include <math.h>

#define N_ROWS 4096
#define DIM    256
#define NLAYER 4
#define KSPLIT 8
#define COLS_PER_SPLIT (N_ROWS / KSPLIT)
#define QBLK 64
#define KBLK 32
#define GN_CHUNKS 16

typedef __attribute__((ext_vector_type(8))) short bf16x8;
typedef __attribute__((ext_vector_type(4))) short bf16x4;
typedef __attribute__((ext_vector_type(4))) float f32x4;

__device__ __forceinline__ unsigned short f2b(float f) {
  unsigned int u = __float_as_uint(f);
  unsigned int r = (u + 0x7fffu + ((u >> 16) & 1u)) >> 16;
  return (unsigned short)r;
}

// ---------------------------------------------------------------------------
// f32 -> bf16 convert (vectorized), n multiple of 1024
// ---------------------------------------------------------------------------
__global__ void cvt_f2b_kernel(const float* __restrict__ in,
                               unsigned short* __restrict__ out) {
  int i = blockIdx.x * 256 + threadIdx.x;
  float4 v = ((const float4*)in)[i];
  ushort4 u;
  u.x = f2b(v.x);
  u.y = f2b(v.y);
  u.z = f2b(v.z);
  u.w = f2b(v.w);
  ((ushort4*)out)[i] = u;
}

// ---------------------------------------------------------------------------
// MFMA NT GEMM: C[M,256] = A[M,256](bf16) @ B[256,256]^T(bf16) (+bias)(+res f32)
// grid (M/64, 4), block 256 = 4 waves (2x2), wave = 32x32 tile.
// ---------------------------------------------------------------------------
__global__ __launch_bounds__(256) void mfma_nt_kernel(
    const unsigned short* __restrict__ A, const unsigned short* __restrict__ Bm,
    const float* __restrict__ bias, const float* __restrict__ res,
    float* __restrict__ C, unsigned short* __restrict__ Cb) {
  __shared__ __align__(16) short Al[64 * 32];
  __shared__ __align__(16) short Bl[64 * 32];
  const int tid = threadIdx.x;
  const int wv = tid >> 6, lane = tid & 63;
  const int cl = lane & 15, gq = lane >> 4;
  const int wr = wv >> 1, wc = wv & 1;
  const int m0 = blockIdx.x * 64, n0 = blockIdx.y * 64;
  f32x4 acc[2][2];
#pragma unroll
  for (int mi = 0; mi < 2; ++mi)
#pragma unroll
    for (int ni = 0; ni < 2; ++ni) acc[mi][ni] = (f32x4){0.f, 0.f, 0.f, 0.f};
  for (int k0 = 0; k0 < DIM; k0 += 32) {
    __syncthreads();
    {
      int r = tid >> 2, c = tid & 3;
      *(bf16x8*)&Al[r * 32 + c * 8] =
          *(const bf16x8*)&A[(size_t)(m0 + r) * DIM + k0 + c * 8];
      *(bf16x8*)&Bl[r * 32 + c * 8] =
          *(const bf16x8*)&Bm[(size_t)(n0 + r) * DIM + k0 + c * 8];
    }
    __syncthreads();
    bf16x8 af[2], bfr[2];
#pragma unroll
    for (int mi = 0; mi < 2; ++mi)
      af[mi] = *(const bf16x8*)&Al[(wr * 32 + mi * 16 + cl) * 32 + gq * 8];
#pragma unroll
    for (int ni = 0; ni < 2; ++ni)
      bfr[ni] = *(const bf16x8*)&Bl[(wc * 32 + ni * 16 + cl) * 32 + gq * 8];
#pragma unroll
    for (int mi = 0; mi < 2; ++mi)
#pragma unroll
      for (int ni = 0; ni < 2; ++ni)
        acc[mi][ni] = __builtin_amdgcn_mfma_f32_16x16x32_bf16(
            af[mi], bfr[ni], acc[mi][ni], 0, 0, 0);
  }
#pragma unroll
  for (int mi = 0; mi < 2; ++mi)
#pragma unroll
    for (int ni = 0; ni < 2; ++ni)
#pragma unroll
      for (int i = 0; i < 4; ++i) {
        int row = m0 + wr * 32 + mi * 16 + gq * 4 + i;
        int col = n0 + wc * 32 + ni * 16 + cl;
        float v = acc[mi][ni][i];
        if (bias) v += bias[col];
        if (res) v += res[(size_t)row * DIM + col];
        C[(size_t)row * DIM + col] = v;
        if (Cb) Cb[(size_t)row * DIM + col] = f2b(v);
      }
}

// Fused QKV MFMA: blockIdx.z selects weights/bias/outputs; bf16 side-out Q,K
__global__ __launch_bounds__(256) void mfma_qkv_kernel(
    const unsigned short* __restrict__ A, const unsigned short* __restrict__ W0,
    const unsigned short* __restrict__ W1, const unsigned short* __restrict__ W2,
    const float* __restrict__ b0, const float* __restrict__ b1,
    const float* __restrict__ b2, float* __restrict__ C0,
    float* __restrict__ C1, float* __restrict__ C2,
    unsigned short* __restrict__ Qb16, unsigned short* __restrict__ Kb16) {
  const unsigned short* Bm = (blockIdx.z == 0) ? W0 : (blockIdx.z == 1) ? W1 : W2;
  const float* bias = (blockIdx.z == 0) ? b0 : (blockIdx.z == 1) ? b1 : b2;
  float* C = (blockIdx.z == 0) ? C0 : (blockIdx.z == 1) ? C1 : C2;
  unsigned short* Cb =
      (blockIdx.z == 0) ? Qb16 : (blockIdx.z == 1) ? Kb16 : nullptr;
  __shared__ __align__(16) short Al[64 * 32];
  __shared__ __align__(16) short Bl[64 * 32];
  const int tid = threadIdx.x;
  const int wv = tid >> 6, lane = tid & 63;
  const int cl = lane & 15, gq = lane >> 4;
  const int wr = wv >> 1, wc = wv & 1;
  const int m0 = blockIdx.x * 64, n0 = blockIdx.y * 64;
  f32x4 acc[2][2];
#pragma unroll
  for (int mi = 0; mi < 2; ++mi)
#pragma unroll
    for (int ni = 0; ni < 2; ++ni) acc[mi][ni] = (f32x4){0.f, 0.f, 0.f, 0.f};
  for (int k0 = 0; k0 < DIM; k0 += 32) {
    __syncthreads();
    {
      int r = tid >> 2, c = tid & 3;
      *(bf16x8*)&Al[r * 32 + c * 8] =
          *(const bf16x8*)&A[(size_t)(m0 + r) * DIM + k0 + c * 8];
      *(bf16x8*)&Bl[r * 32 + c * 8] =
          *(const bf16x8*)&Bm[(size_t)(n0 + r) * DIM + k0 + c * 8];
    }
    __syncthreads();
    bf16x8 af[2], bfr[2];
#pragma unroll
    for (int mi = 0; mi < 2; ++mi)
      af[mi] = *(const bf16x8*)&Al[(wr * 32 + mi * 16 + cl) * 32 + gq * 8];
#pragma unroll
    for (int ni = 0; ni < 2; ++ni)
      bfr[ni] = *(const bf16x8*)&Bl[(wc * 32 + ni * 16 + cl) * 32 + gq * 8];
#pragma unroll
    for (int mi = 0; mi < 2; ++mi)
#pragma unroll
      for (int ni = 0; ni < 2; ++ni)
        acc[mi][ni] = __builtin_amdgcn_mfma_f32_16x16x32_bf16(
            af[mi], bfr[ni], acc[mi][ni], 0, 0, 0);
  }
#pragma unroll
  for (int mi = 0; mi < 2; ++mi)
#pragma unroll
    for (int ni = 0; ni < 2; ++ni)
#pragma unroll
      for (int i = 0; i < 4; ++i) {
        int row = m0 + wr * 32 + mi * 16 + gq * 4 + i;
        int col = n0 + wc * 32 + ni * 16 + cl;
        float v = acc[mi][ni][i] + bias[col];
        C[(size_t)row * DIM + col] = v;
        if (Cb) Cb[(size_t)row * DIM + col] = f2b(v);
      }
}

// ---------------------------------------------------------------------------
// ksum = column sum of K (2-stage, 64-way)
// ---------------------------------------------------------------------------
__global__ void ksum_part_kernel(const float* __restrict__ K,
                                 float* __restrict__ kpart) {
  int d = threadIdx.x, b = blockIdx.x;
  float s = 0.f;
  int base = b * 64;
  for (int n = 0; n < 64; ++n) s += K[(size_t)(base + n) * DIM + d];
  kpart[b * DIM + d] = s;
}
__global__ void ksum_red_kernel(const float* __restrict__ kpart,
                                float* __restrict__ ksum) {
  int d = threadIdx.x;
  float s = 0.f;
  for (int b = 0; b < 64; ++b) s += kpart[b * DIM + d];
  ksum[d] = s;
}

// ---------------------------------------------------------------------------
// Mpart[z] = K[z*512:(z+1)*512,:]^T @ K[...] ; grid(4,4,8)  (f32 for accuracy)
// ---------------------------------------------------------------------------
__global__ __launch_bounds__(256) void mpart_kernel(const float* __restrict__ K,
                                                    float* __restrict__ Mpart) {
  __shared__ float Ka[32][65];
  __shared__ float Kb[32][65];
  const int a0 = blockIdx.x * 64, b0 = blockIdx.y * 64, z = blockIdx.z;
  const int tid = threadIdx.x;
  const int tx = tid & 15, ty = tid >> 4;
  float acc[4][4] = {};
  for (int nb = 0; nb < 512; nb += 32) {
    __syncthreads();
#pragma unroll
    for (int i = 0; i < 8; ++i) {
      int e = tid + i * 256;
      int nr = e >> 6, cc = e & 63;
      size_t rowoff = (size_t)(z * 512 + nb + nr) * DIM;
      Ka[nr][cc] = K[rowoff + a0 + cc];
      Kb[nr][cc] = K[rowoff + b0 + cc];
    }
    __syncthreads();
#pragma unroll
    for (int kk = 0; kk < 32; ++kk) {
      float a[4], b[4];
#pragma unroll
      for (int r = 0; r < 4; ++r) a[r] = Ka[kk][ty + r * 16];
#pragma unroll
      for (int c = 0; c < 4; ++c) b[c] = Kb[kk][tx + c * 16];
#pragma unroll
      for (int r = 0; r < 4; ++r)
#pragma unroll
        for (int c = 0; c < 4; ++c) acc[r][c] = fmaf(a[r], b[c], acc[r][c]);
    }
  }
#pragma unroll
  for (int r = 0; r < 4; ++r)
#pragma unroll
    for (int c = 0; c < 4; ++c)
      Mpart[((size_t)z << 16) + (size_t)(a0 + ty + r * 16) * DIM + b0 + tx +
            c * 16] = acc[r][c];
}
__global__ void mreduce_kernel(const float* __restrict__ Mp,
                               float* __restrict__ Mm,
                               unsigned short* __restrict__ Mb) {
  int e = blockIdx.x * 256 + threadIdx.x;
  float s = 0.f;
#pragma unroll
  for (int z = 0; z < 8; ++z) s += Mp[(size_t)z * 65536 + e];
  Mm[e] = s;
  Mb[e] = f2b(s);
}

// ---------------------------------------------------------------------------
// Per-row att mean / inv-std
// ---------------------------------------------------------------------------
__global__ __launch_bounds__(256) void stats_kernel(
    const float* __restrict__ q, const float* __restrict__ tb,
    const float* __restrict__ ksum, const int* __restrict__ tptr,
    float* __restrict__ meanv, float* __restrict__ istdv) {
  const int wave = threadIdx.x >> 6, lane = threadIdx.x & 63;
  const int row = blockIdx.x * 4 + wave;
  const float4 qv = ((const float4*)(q + (size_t)row * DIM))[lane];
  const float4 tv4 = ((const float4*)(tb + (size_t)row * DIM))[lane];
  const float4 kv = ((const float4*)ksum)[lane];
  float p1 = qv.x * kv.x + qv.y * kv.y + qv.z * kv.z + qv.w * kv.w;
  float p2 = tv4.x * qv.x + tv4.y * qv.y + tv4.z * qv.z + tv4.w * qv.w;
#pragma unroll
  for (int off = 32; off >= 1; off >>= 1) {
    p1 += __shfl_xor(p1, off);
    p2 += __shfl_xor(p2, off);
  }
  if (lane == 0) {
    float tt = (float)tptr[0];
    float sc = 1.f / (16.f * tt);
    float mean = p1 * sc * (1.f / (float)N_ROWS);
    float e2 = p2 * sc * sc * (1.f / (float)N_ROWS);
    float var = fmaxf(e2 - mean * mean, 0.f);
    meanv[row] = mean;
    istdv[row] = 1.f / (sqrtf(var) + 1e-5f);
  }
}

__global__ void prep_kernel(const float* __restrict__ yhat,
                            float* __restrict__ logy) {
  int i = blockIdx.x * 256 + threadIdx.x;
  logy[i] = logf(yhat[i] + 1e-9f);
}

// ---------------------------------------------------------------------------
// Pack (dmask & bmask) into bits (masks are int32 on device)
// ---------------------------------------------------------------------------
__global__ void maskpack_kernel(const int* __restrict__ dmask,
                                const int* __restrict__ bmask,
                                unsigned int* __restrict__ mbits) {
  int gid = blockIdx.x * 256 + threadIdx.x;
  bool v = (dmask[gid] != 0) && (bmask[gid] != 0);
  unsigned long long bal = __ballot(v);
  if ((threadIdx.x & 63) == 0) {
    int w = gid >> 5;
    mbits[w] = (unsigned int)(bal & 0xffffffffu);
    mbits[w + 1] = (unsigned int)(bal >> 32);
  }
}

// ---------------------------------------------------------------------------
// Transpose V f32[4096,256] -> Vt bf16[256,4096]
// ---------------------------------------------------------------------------
__global__ __launch_bounds__(256) void vt_kernel(
    const float* __restrict__ V, unsigned short* __restrict__ Vtb) {
  __shared__ float T[64][65];
  const int n0 = blockIdx.x * 64, d0 = blockIdx.y * 64;
  const int tx = threadIdx.x & 63, ty = threadIdx.x >> 6;
#pragma unroll
  for (int p = 0; p < 16; ++p)
    T[ty + p * 4][tx] = V[(size_t)(n0 + ty + p * 4) * DIM + d0 + tx];
  __syncthreads();
#pragma unroll
  for (int p = 0; p < 16; ++p)
    Vtb[(size_t)(d0 + ty + p * 4) * N_ROWS + n0 + tx] = f2b(T[tx][ty + p * 4]);
}

// ---------------------------------------------------------------------------
// MFMA flash mean-shift attention. grid (64, KSPLIT), block 256 (4 waves).
// LDS strides chosen conflict-free: Kl 288 (144 dw = 16 mod 32),
// Vtl/Pl 32 (contiguous wave reads).
// ---------------------------------------------------------------------------
__global__ __launch_bounds__(256) void flash_mfma_kernel(
    const unsigned short* __restrict__ Qb, const unsigned short* __restrict__ Kb,
    const unsigned short* __restrict__ Vtb, const float* __restrict__ xyzc,
    const float* __restrict__ logy, const float* __restrict__ meanv,
    const float* __restrict__ istdv, const unsigned int* __restrict__ mbits,
    const int* __restrict__ tptr, const float* __restrict__ bwp,
    const int* __restrict__ usestdp, const int* __restrict__ selfdp,
    unsigned short* __restrict__ paccb, float* __restrict__ pm,
    float* __restrict__ ps, float* __restrict__ pax) {
  __shared__ __align__(16) short Kl[32 * 288];
  __shared__ __align__(16) short Vtl[256 * 32];
  __shared__ __align__(16) short Pl[4][16 * 32];
  __shared__ float xyz_t[32][3];
  __shared__ float sqt[32];
  __shared__ float logyt[32];

  const int tid = threadIdx.x;
  const int wv = tid >> 6, lane = tid & 63;
  const int cl = lane & 15, gq = lane >> 4;
  const int r0 = blockIdx.x * QBLK + wv * 16;
  const int split = blockIdx.y;
  const int colbase = split * COLS_PER_SPLIT;

  const float tv = (float)tptr[0];
  const float scale = 1.f / (16.f * tv);
  const float bw = bwp[0];
  const float inv2bw2 = 1.f / (2.f * bw * bw);
  const int usestd = usestdp[0];
  const float selfd = (float)selfdp[0];

  bf16x8 qa[8];
  {
    const bf16x8* qp = (const bf16x8*)(Qb + (size_t)(r0 + cl) * DIM);
#pragma unroll
    for (int ks = 0; ks < 8; ++ks) qa[ks] = qp[ks * 4 + gq];
  }
  int rowg[4];
  float mrow[4], irow[4], xr[4][3], sqrow[4];
#pragma unroll
  for (int i = 0; i < 4; ++i) {
    rowg[i] = r0 + gq * 4 + i;
    mrow[i] = meanv[rowg[i]];
    irow[i] = istdv[rowg[i]];
    xr[i][0] = xyzc[(size_t)rowg[i] * 3 + 0];
    xr[i][1] = xyzc[(size_t)rowg[i] * 3 + 1];
    xr[i][2] = xyzc[(size_t)rowg[i] * 3 + 2];
    sqrow[i] =
        xr[i][0] * xr[i][0] + xr[i][1] * xr[i][1] + xr[i][2] * xr[i][2];
  }
  float m[4], s[4], ax[4][3];
  f32x4 o[16];
#pragma unroll
  for (int i = 0; i < 4; ++i) {
    m[i] = -INFINITY;
    s[i] = 0.f;
    ax[i][0] = ax[i][1] = ax[i][2] = 0.f;
  }
#pragma unroll
  for (int dt = 0; dt < 16; ++dt) o[dt] = (f32x4){0.f, 0.f, 0.f, 0.f};

  for (int tt = 0; tt < COLS_PER_SPLIT; tt += KBLK) {
    const int t0g = colbase + tt;
    __syncthreads();
    {
      const bf16x8* kg = (const bf16x8*)(Kb + (size_t)t0g * DIM);
#pragma unroll
      for (int p = 0; p < 4; ++p) {
        int cid = tid + p * 256;
        int r = cid >> 5, c = cid & 31;
        *(bf16x8*)&Kl[r * 288 + c * 8] = kg[r * 32 + c];
      }
#pragma unroll
      for (int p = 0; p < 8; ++p) {
        int cid = tid + p * 256;
        int d = cid >> 3, c4 = cid & 7;
        *(bf16x4*)&Vtl[d * 32 + c4 * 4] =
            *(const bf16x4*)&Vtb[(size_t)d * N_ROWS + t0g + c4 * 4];
      }
      if (tid < 32) {
        float a0 = xyzc[(size_t)(t0g + tid) * 3 + 0];
        float a1 = xyzc[(size_t)(t0g + tid) * 3 + 1];
        float a2 = xyzc[(size_t)(t0g + tid) * 3 + 2];
        xyz_t[tid][0] = a0;
        xyz_t[tid][1] = a1;
        xyz_t[tid][2] = a2;
        sqt[tid] = a0 * a0 + a1 * a1 + a2 * a2;
      } else if (tid < 64) {
        logyt[tid - 32] = logy[t0g + tid - 32];
      }
    }
    __syncthreads();

    f32x4 st[2];
    st[0] = (f32x4){0.f, 0.f, 0.f, 0.f};
    st[1] = (f32x4){0.f, 0.f, 0.f, 0.f};
#pragma unroll
    for (int ct = 0; ct < 2; ++ct)
#pragma unroll
      for (int ks = 0; ks < 8; ++ks) {
        bf16x8 kf =
            *(const bf16x8*)&Kl[(ct * 16 + cl) * 288 + ks * 32 + gq * 8];
        st[ct] =
            __builtin_amdgcn_mfma_f32_16x16x32_bf16(qa[ks], kf, st[ct], 0, 0, 0);
      }

    unsigned int mw[4];
#pragma unroll
    for (int i = 0; i < 4; ++i)
      mw[i] = mbits[((size_t)rowg[i] << 7) + (t0g >> 5)];

    float corr4[4];
#pragma unroll
    for (int i = 0; i < 4; ++i) {
      float lg0 = 0.f, lg1 = 0.f;
#pragma unroll
      for (int ct = 0; ct < 2; ++ct) {
        int col = ct * 16 + cl;
        float att = st[ct][i] * scale;
        float a = usestd ? (att - mrow[i]) * irow[i] : att;
        float d3 = xr[i][0] * xyz_t[col][0] + xr[i][1] * xyz_t[col][1] +
                   xr[i][2] * xyz_t[col][2];
        float d2 = sqrow[i] + sqt[col] - 2.f * d3;
        d2 = fmaxf(d2, 0.f);
        if (rowg[i] == t0g + col) d2 += selfd;
        float logit = a - d2 * inv2bw2 + logyt[col];
        if (!((mw[i] >> col) & 1u)) logit = -1e9f;
        if (ct == 0) lg0 = logit; else lg1 = logit;
      }
      float tm = fmaxf(lg0, lg1);
      tm = fmaxf(tm, __shfl_xor(tm, 1));
      tm = fmaxf(tm, __shfl_xor(tm, 2));
      tm = fmaxf(tm, __shfl_xor(tm, 4));
      tm = fmaxf(tm, __shfl_xor(tm, 8));
      float nm = fmaxf(m[i], tm);
      float corr = __expf(m[i] - nm);
      float p0 = __expf(lg0 - nm);
      float p1 = __expf(lg1 - nm);
      float es = p0 + p1;
      es += __shfl_xor(es, 1);
      es += __shfl_xor(es, 2);
      es += __shfl_xor(es, 4);
      es += __shfl_xor(es, 8);
      s[i] = s[i] * corr + es;
      m[i] = nm;
      corr4[i] = corr;
      ax[i][0] = ax[i][0] * corr + p0 * xyz_t[cl][0] + p1 * xyz_t[16 + cl][0];
      ax[i][1] = ax[i][1] * corr + p0 * xyz_t[cl][1] + p1 * xyz_t[16 + cl][1];
      ax[i][2] = ax[i][2] * corr + p0 * xyz_t[cl][2] + p1 * xyz_t[16 + cl][2];
      Pl[wv][(gq * 4 + i) * 32 + cl] = (short)f2b(p0);
      Pl[wv][(gq * 4 + i) * 32 + 16 + cl] = (short)f2b(p1);
    }
#pragma unroll
    for (int dt = 0; dt < 16; ++dt) {
      o[dt][0] *= corr4[0];
      o[dt][1] *= corr4[1];
      o[dt][2] *= corr4[2];
      o[dt][3] *= corr4[3];
    }
    bf16x8 pf = *(const bf16x8*)&Pl[wv][cl * 32 + gq * 8];
#pragma unroll
    for (int dt = 0; dt < 16; ++dt) {
      bf16x8 vf = *(const bf16x8*)&Vtl[(dt * 16 + cl) * 32 + gq * 8];
      o[dt] = __builtin_amdgcn_mfma_f32_16x16x32_bf16(pf, vf, o[dt], 0, 0, 0);
    }
  }

#pragma unroll
  for (int i = 0; i < 4; ++i)
#pragma unroll
    for (int c = 0; c < 3; ++c) {
      float v = ax[i][c];
      v += __shfl_xor(v, 1);
      v += __shfl_xor(v, 2);
      v += __shfl_xor(v, 4);
      v += __shfl_xor(v, 8);
      ax[i][c] = v;
    }
  if (cl == 0) {
#pragma unroll
    for (int i = 0; i < 4; ++i) {
      size_t idx = (size_t)split * N_ROWS + rowg[i];
      pm[idx] = m[i];
      ps[idx] = s[i];
      pax[idx * 3 + 0] = ax[i][0];
      pax[idx * 3 + 1] = ax[i][1];
      pax[idx * 3 + 2] = ax[i][2];
    }
  }
#pragma unroll
  for (int dt = 0; dt < 16; ++dt)
#pragma unroll
    for (int i = 0; i < 4; ++i)
      paccb[((size_t)split * N_ROWS + rowg[i]) * DIM + dt * 16 + cl] =
          f2b(o[dt][i]);
}

// ---------------------------------------------------------------------------
// Merge KSPLIT partials (exact log-sum-exp combine) -> x_att bf16, xyz update
// ---------------------------------------------------------------------------
__global__ __launch_bounds__(256) void merge8_kernel(
    const unsigned short* __restrict__ paccb, const float* __restrict__ pm,
    const float* __restrict__ ps, const float* __restrict__ pax,
    const float* __restrict__ xyzc, const float* __restrict__ betap,
    unsigned short* __restrict__ xattb, float* __restrict__ xyz_out) {
  const int wvl = threadIdx.x >> 6, lane = threadIdx.x & 63;
  const int row = blockIdx.x * 4 + wvl;
  float mk[KSPLIT], sk[KSPLIT], fk[KSPLIT];
#pragma unroll
  for (int k = 0; k < KSPLIT; ++k) {
    mk[k] = pm[(size_t)k * N_ROWS + row];
    sk[k] = ps[(size_t)k * N_ROWS + row];
  }
  float mg = mk[0];
#pragma unroll
  for (int k = 1; k < KSPLIT; ++k) mg = fmaxf(mg, mk[k]);
  float den = 0.f;
#pragma unroll
  for (int k = 0; k < KSPLIT; ++k) {
    fk[k] = __expf(mk[k] - mg);
    den += sk[k] * fk[k];
  }
  float inv = 1.f / den;
  float a0 = 0.f, a1 = 0.f, a2 = 0.f, a3 = 0.f;
#pragma unroll
  for (int k = 0; k < KSPLIT; ++k) {
    const unsigned short* p =
        &paccb[((size_t)k * N_ROWS + row) * DIM + lane * 4];
    uint2 u = *(const uint2*)p;
    float b0 = __uint_as_float((u.x & 0xffffu) << 16);
    float b1 = __uint_as_float(u.x & 0xffff0000u);
    float b2 = __uint_as_float((u.y & 0xffffu) << 16);
    float b3 = __uint_as_float(u.y & 0xffff0000u);
    a0 = fmaf(b0, fk[k], a0);
    a1 = fmaf(b1, fk[k], a1);
    a2 = fmaf(b2, fk[k], a2);
    a3 = fmaf(b3, fk[k], a3);
  }
  ushort4 ov;
  ov.x = f2b(a0 * inv);
  ov.y = f2b(a1 * inv);
  ov.z = f2b(a2 * inv);
  ov.w = f2b(a3 * inv);
  *(ushort4*)&xattb[(size_t)row * DIM + lane * 4] = ov;
  if (lane < 3) {
    float axs = 0.f;
#pragma unroll
    for (int k = 0; k < KSPLIT; ++k)
      axs += pax[((size_t)k * N_ROWS + row) * 3 + lane] * fk[k];
    float beta = betap[0];
    xyz_out[(size_t)row * 3 + lane] =
        beta * axs * inv + (1.f - beta) * xyzc[(size_t)row * 3 + lane];
  }
}

// ---------------------------------------------------------------------------
// GraphNorm: two-stage parallel stats, then apply (f32 + bf16 side output)
// ---------------------------------------------------------------------------
__global__ __launch_bounds__(256) void gn_part_kernel(
    const float* __restrict__ X, const int* __restrict__ cums,
    float* __restrict__ gpart) {
  const int seg = blockIdx.x, chunk = blockIdx.y, d = threadIdx.x;
  const int r0 = cums[seg], r1 = cums[seg + 1];
  const int cnt = r1 - r0;
  const int per = (cnt + GN_CHUNKS - 1) / GN_CHUNKS;
  const int a = r0 + chunk * per;
  const int b = min(a + per, r1);
  float s = 0.f, ss = 0.f;
  for (int r = a; r < b; ++r) {
    float v = X[(size_t)r * DIM + d];
    s += v;
    ss += v * v;
  }
  gpart[(((size_t)seg * GN_CHUNKS + chunk) * 2 + 0) * DIM + d] = s;
  gpart[(((size_t)seg * GN_CHUNKS + chunk) * 2 + 1) * DIM + d] = ss;
}

__global__ void gn_red_kernel(const float* __restrict__ gpart,
                              const int* __restrict__ cums,
                              float* __restrict__ gm, float* __restrict__ gi) {
  const int seg = blockIdx.x, d = threadIdx.x;
  float s = 0.f, ss = 0.f;
#pragma unroll
  for (int c = 0; c < GN_CHUNKS; ++c) {
    s += gpart[(((size_t)seg * GN_CHUNKS + c) * 2 + 0) * DIM + d];
    ss += gpart[(((size_t)seg * GN_CHUNKS + c) * 2 + 1) * DIM + d];
  }
  float cnt = (float)(cums[seg + 1] - cums[seg]);
  float mean = s / fmaxf(cnt, 1.f);
  float var = (ss - cnt * mean * mean) / fmaxf(cnt - 1.f, 1.f);
  gm[seg * DIM + d] = mean;
  gi[seg * DIM + d] = 1.f / (sqrtf(fmaxf(var, 0.f)) + 1e-5f);
}

__global__ __launch_bounds__(256) void gn_apply_kernel(
    const float* __restrict__ X, const float* __restrict__ gamma,
    const float* __restrict__ betag, const int* __restrict__ cums, int nseg,
    const float* __restrict__ gm, const float* __restrict__ gi,
    float* __restrict__ Xout, unsigned short* __restrict__ Xb,
    float* __restrict__ ofinal) {
  int idx = blockIdx.x * 256 + threadIdx.x;
  int base = idx * 4;
  int row = base >> 8, d0 = base & 255;
  int seg = 0;
  for (int b = 1; b <= nseg; ++b) seg += (row >= cums[b]) ? 1 : 0;
  float4 x = ((const float4*)X)[idx];
  float xs[4] = {x.x, x.y, x.z, x.w};
  const float* gmp = gm + seg * DIM + d0;
  const float* gip = gi + seg * DIM + d0;
  float o[4];
#pragma unroll
  for (int c = 0; c < 4; ++c)
    o[c] = gamma[d0 + c] * (xs[c] - gmp[c]) * gip[c] + betag[d0 + c];
  float4 ov = {o[0], o[1], o[2], o[3]};
  ((float4*)Xout)[idx] = ov;
  ushort4 ub;
  ub.x = f2b(o[0]);
  ub.y = f2b(o[1]);
  ub.z = f2b(o[2]);
  ub.w = f2b(o[3]);
  ((ushort4*)Xb)[idx] = ub;
  if (ofinal) ((float4*)ofinal)[idx] = ov;
}

// ---------------------------------------------------------------------------
extern "C" void kernel_launch(void* const* d_in, const int* in_sizes, int n_in,
                              void* d_out, int out_size, void* d_ws,
                              size_t ws_size, hipStream_t stream) {
  const float* xyz0 = (const float*)d_in[0];
  const float* x0 = (const float*)d_in[1];
  const float* yhat = (const float*)d_in[2];
  const int* dmask = (const int*)d_in[3];
  const int* tptr = (const int*)d_in[4];
  const float* bwp = (const float*)d_in[5];
  const float* betap = (const float*)d_in[6];
  const int* cums = (const int*)d_in[7];
  const int* bmask = (const int*)d_in[8];
  const int* usestdp = (const int*)d_in[9];
  const int* selfdp = (const int*)d_in[10];
  const float* qw = (const float*)d_in[11];
  const float* kw = (const float*)d_in[12];
  const float* vw = (const float*)d_in[13];
  const float* ow = (const float*)d_in[14];
  const float* qbv = (const float*)d_in[15];
  const float* kbv = (const float*)d_in[16];
  const float* vbv = (const float*)d_in[17];
  const float* obv = (const float*)d_in[18];
  const float* gamma = (const float*)d_in[19];
  const float* betag = (const float*)d_in[20];
  float* out = (float*)d_out;
  float* ws = (float*)d_ws;

  const size_t ND = (size_t)N_ROWS * DIM;  // 1,048,576
  const size_t WSZ = (size_t)NLAYER * DIM * DIM;  // 262,144
  float* bq = ws + 0 * ND;
  float* bk = ws + 1 * ND;
  float* bv = ws + 2 * ND;
  float* bt = ws + 3 * ND;  // Q@M f32 (dead during flash)
  float* bh = ws + 4 * ND;  // hosts Qb16+Kb16
  float* bx = ws + 5 * ND;  // layer output f32
  float* Mp = ws + 6 * ND;          // 2 MB (hosts Vtb during flash)
  float* Mm = Mp + 8 * 65536;       // 65536
  float* kpart = Mm + 65536;        // 64*256
  float* ksum = kpart + 64 * 256;   // 256
  float* meanv = ksum + 256;        // 4096
  float* istdv = meanv + 4096;      // 4096
  float* gm = istdv + 4096;         // 8*256
  float* gi = gm + 8 * 256;         // 8*256
  float* logy = gi + 8 * 256;       // 4096
  float* xyzA = logy + 4096;        // 4096*3
  float* xyzB = xyzA + 3 * N_ROWS;  // 4096*3
  unsigned int* mbits = (unsigned int*)(xyzB + 3 * N_ROWS);  // 4096*128 u32
  float* pm = (float*)(mbits + (size_t)N_ROWS * 128);        // 8*4096
  float* ps = pm + (size_t)KSPLIT * N_ROWS;                  // 8*4096
  float* pax = ps + (size_t)KSPLIT * N_ROWS;                 // 8*4096*3
  float* gpart = pax + (size_t)KSPLIT * N_ROWS * 3;          // 8*16*2*256
  unsigned short* Mb16 = (unsigned short*)(gpart + 8 * GN_CHUNKS * 2 * DIM);
  unsigned short* qwb = Mb16 + 65536;
  unsigned short* kwb = qwb + WSZ;
  unsigned short* vwb = kwb + WSZ;
  unsigned short* owb = vwb + WSZ;
  unsigned short* xinb = owb + WSZ;   // ND shorts
  unsigned short* xattb = xinb + ND;  // ND shorts

  unsigned short* paccb = (unsigned short*)ws;  // 16 MB over bq..bt
  unsigned short* Qb16 = (unsigned short*)bh;   // 2 MB
  unsigned short* Kb16 = Qb16 + ND;             // 2 MB
  unsigned short* Vtb = (unsigned short*)Mp;    // 2 MB (exact fit)
  float* bo = bv;                               // O-proj output (f32)

  const int nseg = in_sizes[7] - 1;

  prep_kernel<<<16, 256, 0, stream>>>(yhat, logy);
  maskpack_kernel<<<65536, 256, 0, stream>>>(dmask, bmask, mbits);
  cvt_f2b_kernel<<<256, 256, 0, stream>>>(qw, qwb);
  cvt_f2b_kernel<<<256, 256, 0, stream>>>(kw, kwb);
  cvt_f2b_kernel<<<256, 256, 0, stream>>>(vw, vwb);
  cvt_f2b_kernel<<<256, 256, 0, stream>>>(ow, owb);
  cvt_f2b_kernel<<<1024, 256, 0, stream>>>(x0, xinb);

  for (int l = 0; l < NLAYER; ++l) {
    const float* xin = (l == 0) ? x0 : bx;
    const float* xyz_in = (l == 0) ? xyz0 : ((l & 1) ? xyzB : xyzA);
    float* xyz_o = (l & 1) ? xyzA : xyzB;
    const size_t wo = (size_t)l * DIM * DIM;

    mfma_qkv_kernel<<<dim3(64, 4, 3), 256, 0, stream>>>(
        xinb, qwb + wo, kwb + wo, vwb + wo, qbv + l * DIM, kbv + l * DIM,
        vbv + l * DIM, bq, bk, bv, Qb16, Kb16);
    ksum_part_kernel<<<64, 256, 0, stream>>>(bk, kpart);
    ksum_red_kernel<<<1, 256, 0, stream>>>(kpart, ksum);
    mpart_kernel<<<dim3(4, 4, 8), 256, 0, stream>>>(bk, Mp);
    mreduce_kernel<<<256, 256, 0, stream>>>(Mp, Mm, Mb16);
    mfma_nt_kernel<<<dim3(64, 4), 256, 0, stream>>>(Qb16, Mb16, nullptr,
                                                    nullptr, bt, nullptr);
    stats_kernel<<<1024, 256, 0, stream>>>(bq, bt, ksum, tptr, meanv, istdv);
    vt_kernel<<<dim3(64, 4), 256, 0, stream>>>(bv, Vtb);  // Mp now dead
    flash_mfma_kernel<<<dim3(64, KSPLIT), 256, 0, stream>>>(
        Qb16, Kb16, Vtb, xyz_in, logy, meanv, istdv, mbits, tptr, bwp, usestdp,
        selfdp, paccb, pm, ps, pax);
    merge8_kernel<<<1024, 256, 0, stream>>>(paccb, pm, ps, pax, xyz_in, betap,
                                            xattb, xyz_o);
    mfma_nt_kernel<<<dim3(64, 4), 256, 0, stream>>>(xattb, owb + wo,
                                                    obv + l * DIM, xin, bo,
                                                    nullptr);
    gn_part_kernel<<<dim3(nseg, GN_CHUNKS), 256, 0, stream>>>(bo, cums, gpart);
    gn_red_kernel<<<nseg, 256, 0, stream>>>(gpart, cums, gm, gi);
    gn_apply_kernel<<<1024, 256, 0, stream>>>(
        bo, gamma + (size_t)l * DIM, betag + (size_t)l * DIM, cums, nseg, gm,
        gi, bx, xinb, (l == NLAYER - 1) ? out : nullptr);
  }
}

// Round 8
// 654.334 us; speedup vs baseline: 8.0892x; 1.3262x over previous
//
#include <hip/hip_runtime.h>
#include <hip/hip_bf16.h>
#include <math.h>

#define N_ROWS 4096
#define DIM    256
#define NLAYER 4
#define QBLK 64
#define KBLK 32
#define GN_CHUNKS 16

typedef __attribute__((ext_vector_type(8))) short bf16x8;
typedef __attribute__((ext_vector_type(4))) float f32x4;
typedef unsigned short us;

__device__ __forceinline__ us f2b(float f) {
  unsigned int u = __float_as_uint(f);
  unsigned int r = (u + 0x7fffu + ((u >> 16) & 1u)) >> 16;
  return (us)r;
}
__device__ __forceinline__ float b2f(us b) {
  return __uint_as_float(((unsigned int)b) << 16);
}

// ---------------------------------------------------------------------------
__global__ void cvt_f2b_kernel(const float* __restrict__ in,
                               us* __restrict__ out) {
  int i = blockIdx.x * 256 + threadIdx.x;
  float4 v = ((const float4*)in)[i];
  ushort4 u;
  u.x = f2b(v.x);
  u.y = f2b(v.y);
  u.z = f2b(v.z);
  u.w = f2b(v.w);
  ((ushort4*)out)[i] = u;
}

// ---------------------------------------------------------------------------
// MFMA NT GEMM: C[M,256] = A(bf16) @ B(bf16)^T (+bias)(+res f32)
// ---------------------------------------------------------------------------
__global__ __launch_bounds__(256) void mfma_nt_kernel(
    const us* __restrict__ A, const us* __restrict__ Bm,
    const float* __restrict__ bias, const float* __restrict__ res,
    float* __restrict__ C, us* __restrict__ Cb) {
  __shared__ __align__(16) short Al[64 * 32];
  __shared__ __align__(16) short Bl[64 * 32];
  const int tid = threadIdx.x;
  const int wv = tid >> 6, lane = tid & 63;
  const int cl = lane & 15, gq = lane >> 4;
  const int wr = wv >> 1, wc = wv & 1;
  const int m0 = blockIdx.x * 64, n0 = blockIdx.y * 64;
  f32x4 acc[2][2];
#pragma unroll
  for (int mi = 0; mi < 2; ++mi)
#pragma unroll
    for (int ni = 0; ni < 2; ++ni) acc[mi][ni] = (f32x4){0.f, 0.f, 0.f, 0.f};
  for (int k0 = 0; k0 < DIM; k0 += 32) {
    __syncthreads();
    {
      int r = tid >> 2, c = tid & 3;
      *(bf16x8*)&Al[r * 32 + c * 8] =
          *(const bf16x8*)&A[(size_t)(m0 + r) * DIM + k0 + c * 8];
      *(bf16x8*)&Bl[r * 32 + c * 8] =
          *(const bf16x8*)&Bm[(size_t)(n0 + r) * DIM + k0 + c * 8];
    }
    __syncthreads();
    bf16x8 af[2], bfr[2];
#pragma unroll
    for (int mi = 0; mi < 2; ++mi)
      af[mi] = *(const bf16x8*)&Al[(wr * 32 + mi * 16 + cl) * 32 + gq * 8];
#pragma unroll
    for (int ni = 0; ni < 2; ++ni)
      bfr[ni] = *(const bf16x8*)&Bl[(wc * 32 + ni * 16 + cl) * 32 + gq * 8];
#pragma unroll
    for (int mi = 0; mi < 2; ++mi)
#pragma unroll
      for (int ni = 0; ni < 2; ++ni)
        acc[mi][ni] = __builtin_amdgcn_mfma_f32_16x16x32_bf16(
            af[mi], bfr[ni], acc[mi][ni], 0, 0, 0);
  }
#pragma unroll
  for (int mi = 0; mi < 2; ++mi)
#pragma unroll
    for (int ni = 0; ni < 2; ++ni)
#pragma unroll
      for (int i = 0; i < 4; ++i) {
        int row = m0 + wr * 32 + mi * 16 + gq * 4 + i;
        int col = n0 + wc * 32 + ni * 16 + cl;
        float v = acc[mi][ni][i];
        if (bias) v += bias[col];
        if (res) v += res[(size_t)row * DIM + col];
        C[(size_t)row * DIM + col] = v;
        if (Cb) Cb[(size_t)row * DIM + col] = f2b(v);
      }
}

// Fused QKV MFMA (z selects); bf16 side-out for Q,K
__global__ __launch_bounds__(256) void mfma_qkv_kernel(
    const us* __restrict__ A, const us* __restrict__ W0,
    const us* __restrict__ W1, const us* __restrict__ W2,
    const float* __restrict__ b0, const float* __restrict__ b1,
    const float* __restrict__ b2, float* __restrict__ C0,
    float* __restrict__ C1, float* __restrict__ C2, us* __restrict__ Qb16,
    us* __restrict__ Kb16) {
  const us* Bm = (blockIdx.z == 0) ? W0 : (blockIdx.z == 1) ? W1 : W2;
  const float* bias = (blockIdx.z == 0) ? b0 : (blockIdx.z == 1) ? b1 : b2;
  float* C = (blockIdx.z == 0) ? C0 : (blockIdx.z == 1) ? C1 : C2;
  us* Cb = (blockIdx.z == 0) ? Qb16 : (blockIdx.z == 1) ? Kb16 : nullptr;
  __shared__ __align__(16) short Al[64 * 32];
  __shared__ __align__(16) short Bl[64 * 32];
  const int tid = threadIdx.x;
  const int wv = tid >> 6, lane = tid & 63;
  const int cl = lane & 15, gq = lane >> 4;
  const int wr = wv >> 1, wc = wv & 1;
  const int m0 = blockIdx.x * 64, n0 = blockIdx.y * 64;
  f32x4 acc[2][2];
#pragma unroll
  for (int mi = 0; mi < 2; ++mi)
#pragma unroll
    for (int ni = 0; ni < 2; ++ni) acc[mi][ni] = (f32x4){0.f, 0.f, 0.f, 0.f};
  for (int k0 = 0; k0 < DIM; k0 += 32) {
    __syncthreads();
    {
      int r = tid >> 2, c = tid & 3;
      *(bf16x8*)&Al[r * 32 + c * 8] =
          *(const bf16x8*)&A[(size_t)(m0 + r) * DIM + k0 + c * 8];
      *(bf16x8*)&Bl[r * 32 + c * 8] =
          *(const bf16x8*)&Bm[(size_t)(n0 + r) * DIM + k0 + c * 8];
    }
    __syncthreads();
    bf16x8 af[2], bfr[2];
#pragma unroll
    for (int mi = 0; mi < 2; ++mi)
      af[mi] = *(const bf16x8*)&Al[(wr * 32 + mi * 16 + cl) * 32 + gq * 8];
#pragma unroll
    for (int ni = 0; ni < 2; ++ni)
      bfr[ni] = *(const bf16x8*)&Bl[(wc * 32 + ni * 16 + cl) * 32 + gq * 8];
#pragma unroll
    for (int mi = 0; mi < 2; ++mi)
#pragma unroll
      for (int ni = 0; ni < 2; ++ni)
        acc[mi][ni] = __builtin_amdgcn_mfma_f32_16x16x32_bf16(
            af[mi], bfr[ni], acc[mi][ni], 0, 0, 0);
  }
#pragma unroll
  for (int mi = 0; mi < 2; ++mi)
#pragma unroll
    for (int ni = 0; ni < 2; ++ni)
#pragma unroll
      for (int i = 0; i < 4; ++i) {
        int row = m0 + wr * 32 + mi * 16 + gq * 4 + i;
        int col = n0 + wc * 32 + ni * 16 + cl;
        float v = acc[mi][ni][i] + bias[col];
        C[(size_t)row * DIM + col] = v;
        if (Cb) Cb[(size_t)row * DIM + col] = f2b(v);
      }
}

// ---------------------------------------------------------------------------
// Mpart[z] = Kt[:, z*512:+512] @ Kt[:, same]^T  via MFMA; Kt bf16 [256][4096]
// ---------------------------------------------------------------------------
__global__ __launch_bounds__(256) void mpart_mfma_kernel(
    const us* __restrict__ Kt, float* __restrict__ Mp) {
  __shared__ __align__(16) short Al[64 * 32];
  __shared__ __align__(16) short Bl[64 * 32];
  const int tid = threadIdx.x;
  const int wv = tid >> 6, lane = tid & 63;
  const int cl = lane & 15, gq = lane >> 4;
  const int wr = wv >> 1, wc = wv & 1;
  const int a0 = blockIdx.x * 64, b0 = blockIdx.y * 64;
  const int kb = blockIdx.z * 512;
  f32x4 acc[2][2];
#pragma unroll
  for (int mi = 0; mi < 2; ++mi)
#pragma unroll
    for (int ni = 0; ni < 2; ++ni) acc[mi][ni] = (f32x4){0.f, 0.f, 0.f, 0.f};
  for (int k0 = 0; k0 < 512; k0 += 32) {
    __syncthreads();
    {
      int r = tid >> 2, c = tid & 3;
      *(bf16x8*)&Al[r * 32 + c * 8] =
          *(const bf16x8*)&Kt[(size_t)(a0 + r) * N_ROWS + kb + k0 + c * 8];
      *(bf16x8*)&Bl[r * 32 + c * 8] =
          *(const bf16x8*)&Kt[(size_t)(b0 + r) * N_ROWS + kb + k0 + c * 8];
    }
    __syncthreads();
    bf16x8 af[2], bfr[2];
#pragma unroll
    for (int mi = 0; mi < 2; ++mi)
      af[mi] = *(const bf16x8*)&Al[(wr * 32 + mi * 16 + cl) * 32 + gq * 8];
#pragma unroll
    for (int ni = 0; ni < 2; ++ni)
      bfr[ni] = *(const bf16x8*)&Bl[(wc * 32 + ni * 16 + cl) * 32 + gq * 8];
#pragma unroll
    for (int mi = 0; mi < 2; ++mi)
#pragma unroll
      for (int ni = 0; ni < 2; ++ni)
        acc[mi][ni] = __builtin_amdgcn_mfma_f32_16x16x32_bf16(
            af[mi], bfr[ni], acc[mi][ni], 0, 0, 0);
  }
#pragma unroll
  for (int mi = 0; mi < 2; ++mi)
#pragma unroll
    for (int ni = 0; ni < 2; ++ni)
#pragma unroll
      for (int i = 0; i < 4; ++i) {
        int row = a0 + wr * 32 + mi * 16 + gq * 4 + i;
        int col = b0 + wc * 32 + ni * 16 + cl;
        Mp[(size_t)blockIdx.z * 65536 + (size_t)row * DIM + col] =
            acc[mi][ni][i];
      }
}

__global__ void mreduce_kernel(const float* __restrict__ Mp,
                               float* __restrict__ Mm, us* __restrict__ Mb) {
  int e = blockIdx.x * 256 + threadIdx.x;
  float s = 0.f;
#pragma unroll
  for (int z = 0; z < 8; ++z) s += Mp[(size_t)z * 65536 + e];
  Mm[e] = s;
  Mb[e] = f2b(s);
}

// ---------------------------------------------------------------------------
__global__ void ksum_part_kernel(const float* __restrict__ K,
                                 float* __restrict__ kpart) {
  int d = threadIdx.x, b = blockIdx.x;
  float s = 0.f;
  int base = b * 64;
  for (int n = 0; n < 64; ++n) s += K[(size_t)(base + n) * DIM + d];
  kpart[b * DIM + d] = s;
}
__global__ void ksum_red_kernel(const float* __restrict__ kpart,
                                float* __restrict__ ksum) {
  int d = threadIdx.x;
  float s = 0.f;
  for (int b = 0; b < 64; ++b) s += kpart[b * DIM + d];
  ksum[d] = s;
}

// ---------------------------------------------------------------------------
__global__ __launch_bounds__(256) void stats_kernel(
    const float* __restrict__ q, const float* __restrict__ tb,
    const float* __restrict__ ksum, const int* __restrict__ tptr,
    float* __restrict__ meanv, float* __restrict__ istdv) {
  const int wave = threadIdx.x >> 6, lane = threadIdx.x & 63;
  const int row = blockIdx.x * 4 + wave;
  const float4 qv = ((const float4*)(q + (size_t)row * DIM))[lane];
  const float4 tv4 = ((const float4*)(tb + (size_t)row * DIM))[lane];
  const float4 kv = ((const float4*)ksum)[lane];
  float p1 = qv.x * kv.x + qv.y * kv.y + qv.z * kv.z + qv.w * kv.w;
  float p2 = tv4.x * qv.x + tv4.y * qv.y + tv4.z * qv.z + tv4.w * qv.w;
#pragma unroll
  for (int off = 32; off >= 1; off >>= 1) {
    p1 += __shfl_xor(p1, off);
    p2 += __shfl_xor(p2, off);
  }
  if (lane == 0) {
    float tt = (float)tptr[0];
    float sc = 1.f / (16.f * tt);
    float mean = p1 * sc * (1.f / (float)N_ROWS);
    float e2 = p2 * sc * sc * (1.f / (float)N_ROWS);
    float var = fmaxf(e2 - mean * mean, 0.f);
    meanv[row] = mean;
    istdv[row] = 1.f / (sqrtf(var) + 1e-5f);
  }
}

__global__ void prep_kernel(const float* __restrict__ yhat,
                            float* __restrict__ logy) {
  int i = blockIdx.x * 256 + threadIdx.x;
  logy[i] = logf(yhat[i] + 1e-9f);
}

__global__ void maskpack_kernel(const int* __restrict__ dmask,
                                const int* __restrict__ bmask,
                                unsigned int* __restrict__ mbits) {
  int gid = blockIdx.x * 256 + threadIdx.x;
  bool v = (dmask[gid] != 0) && (bmask[gid] != 0);
  unsigned long long bal = __ballot(v);
  if ((threadIdx.x & 63) == 0) {
    int w = gid >> 5;
    mbits[w] = (unsigned int)(bal & 0xffffffffu);
    mbits[w + 1] = (unsigned int)(bal >> 32);
  }
}

// ---------------------------------------------------------------------------
// Transpose f32 [4096,256] -> bf16 [256,4096]
// ---------------------------------------------------------------------------
__global__ __launch_bounds__(256) void vt_kernel(const float* __restrict__ V,
                                                 us* __restrict__ Vtb) {
  __shared__ float T[64][65];
  const int n0 = blockIdx.x * 64, d0 = blockIdx.y * 64;
  const int tx = threadIdx.x & 63, ty = threadIdx.x >> 6;
#pragma unroll
  for (int p = 0; p < 16; ++p)
    T[ty + p * 4][tx] = V[(size_t)(n0 + ty + p * 4) * DIM + d0 + tx];
  __syncthreads();
#pragma unroll
  for (int p = 0; p < 16; ++p)
    Vtb[(size_t)(d0 + ty + p * 4) * N_ROWS + n0 + tx] = f2b(T[tx][ty + p * 4]);
}

// ---------------------------------------------------------------------------
// Flash v3: no-max softmax, identity-contiguous LDS fragment layouts,
// column relabel l = 2*cl+ct. grid (64, nsplit), block 256 (4 waves).
// Outputs RAW partials: o (bf16), s (f32), ax (f32) per split.
// ---------------------------------------------------------------------------
__global__ __launch_bounds__(256) void flash3_kernel(
    const us* __restrict__ Qb, const us* __restrict__ Kb,
    const us* __restrict__ Vtb, const float* __restrict__ xyzc,
    const float* __restrict__ logy, const float* __restrict__ meanv,
    const float* __restrict__ istdv, const unsigned int* __restrict__ mbits,
    const int* __restrict__ tptr, const float* __restrict__ bwp,
    const int* __restrict__ usestdp, const int* __restrict__ selfdp,
    us* __restrict__ plo, us* __restrict__ phi, float* __restrict__ ps,
    float* __restrict__ paxlo, float* __restrict__ paxhi, int cps) {
  __shared__ __align__(16) short Kl[1024 * 8];   // 16 KiB fragment-order
  __shared__ __align__(16) short Vtl[1024 * 8];  // 16 KiB fragment-order
  __shared__ __align__(16) short Pl[4][512];     // 4 KiB

  const int tid = threadIdx.x;
  const int wv = tid >> 6, lane = tid & 63;
  const int cl = lane & 15, gq = lane >> 4;
  const int r0 = blockIdx.x * QBLK + wv * 16;
  const int split = blockIdx.y;
  const int colbase = split * cps;

  const float tv = (float)tptr[0];
  const float scale = 1.f / (16.f * tv);
  const float bw = bwp[0];
  const float inv2bw2 = 1.f / (2.f * bw * bw);
  const float t2 = 2.f * inv2bw2;
  const int usestd = usestdp[0];
  const float sd2 = (float)selfdp[0] * inv2bw2;

  bf16x8 qa[8];
  {
    const bf16x8* qp = (const bf16x8*)(Qb + (size_t)(r0 + cl) * DIM);
#pragma unroll
    for (int ks = 0; ks < 8; ++ks) qa[ks] = qp[ks * 4 + gq];
  }
  int rowg[4];
  float c1[4], cA[4], xr[4][3];
#pragma unroll
  for (int i = 0; i < 4; ++i) {
    rowg[i] = r0 + gq * 4 + i;
    float mrow = meanv[rowg[i]];
    float irow = istdv[rowg[i]];
    c1[i] = usestd ? scale * irow : scale;
    float c2 = usestd ? -mrow * irow : 0.f;
    xr[i][0] = xyzc[(size_t)rowg[i] * 3 + 0];
    xr[i][1] = xyzc[(size_t)rowg[i] * 3 + 1];
    xr[i][2] = xyzc[(size_t)rowg[i] * 3 + 2];
    float sqr = xr[i][0] * xr[i][0] + xr[i][1] * xr[i][1] + xr[i][2] * xr[i][2];
    cA[i] = c2 - sqr * inv2bw2;
  }
  float s[4] = {0.f, 0.f, 0.f, 0.f};
  float ax[4][3] = {};
  f32x4 o[16];
#pragma unroll
  for (int dt = 0; dt < 16; ++dt) o[dt] = (f32x4){0.f, 0.f, 0.f, 0.f};

  const int g0base = 2 * cl;  // local col for ct=0

  for (int tt = 0; tt < cps; tt += KBLK) {
    const int t0g = colbase + tt;
    __syncthreads();
    // stage K (1024 chunks) and V (1024 chunks), identity layout
#pragma unroll
    for (int p = 0; p < 4; ++p) {
      int L = tid + p * 256;
      int ct = L >> 9, ks = (L >> 6) & 7, g = (L >> 4) & 3, c = L & 15;
      *(bf16x8*)&Kl[L * 8] =
          *(const bf16x8*)&Kb[(size_t)(t0g + 2 * c + ct) * DIM + ks * 32 +
                              g * 8];
    }
#pragma unroll
    for (int p = 0; p < 4; ++p) {
      int L = tid + p * 256;
      int dt = L >> 6, g = (L >> 4) & 3, c = L & 15;
      *(bf16x8*)&Vtl[L * 8] =
          *(const bf16x8*)&Vtb[(size_t)(dt * 16 + c) * N_ROWS + t0g + g * 8];
    }
    __syncthreads();

    // per-lane column data (global, L2-resident)
    int gc0 = t0g + g0base, gc1 = gc0 + 1;
    float xa0 = xyzc[(size_t)gc0 * 3 + 0];
    float xa1 = xyzc[(size_t)gc0 * 3 + 1];
    float xa2 = xyzc[(size_t)gc0 * 3 + 2];
    float xb0 = xyzc[(size_t)gc1 * 3 + 0];
    float xb1 = xyzc[(size_t)gc1 * 3 + 1];
    float xb2 = xyzc[(size_t)gc1 * 3 + 2];
    float B0 = logy[gc0] - (xa0 * xa0 + xa1 * xa1 + xa2 * xa2) * inv2bw2;
    float B1 = logy[gc1] - (xb0 * xb0 + xb1 * xb1 + xb2 * xb2) * inv2bw2;

    // QK^T
    f32x4 st0 = (f32x4){0.f, 0.f, 0.f, 0.f};
    f32x4 st1 = (f32x4){0.f, 0.f, 0.f, 0.f};
#pragma unroll
    for (int ks = 0; ks < 8; ++ks) {
      bf16x8 kf0 = *(const bf16x8*)&Kl[(ks * 64 + gq * 16 + cl) * 8];
      st0 = __builtin_amdgcn_mfma_f32_16x16x32_bf16(qa[ks], kf0, st0, 0, 0, 0);
    }
#pragma unroll
    for (int ks = 0; ks < 8; ++ks) {
      bf16x8 kf1 = *(const bf16x8*)&Kl[(512 + ks * 64 + gq * 16 + cl) * 8];
      st1 = __builtin_amdgcn_mfma_f32_16x16x32_bf16(qa[ks], kf1, st1, 0, 0, 0);
    }

#pragma unroll
    for (int i = 0; i < 4; ++i) {
      unsigned int mw = mbits[((size_t)rowg[i] << 7) + (t0g >> 5)];
      unsigned int pb = (mw >> g0base) & 3u;
      float d30 = xr[i][0] * xa0 + xr[i][1] * xa1 + xr[i][2] * xa2;
      float d31 = xr[i][0] * xb0 + xr[i][1] * xb1 + xr[i][2] * xb2;
      float lg0 = fmaf(st0[i], c1[i], cA[i] + B0) + t2 * d30;
      float lg1 = fmaf(st1[i], c1[i], cA[i] + B1) + t2 * d31;
      if (rowg[i] == gc0) lg0 -= sd2;
      if (rowg[i] == gc1) lg1 -= sd2;
      lg0 = (pb & 1u) ? lg0 : -60.f;
      lg1 = (pb & 2u) ? lg1 : -60.f;
      float p0 = __expf(lg0);
      float p1 = __expf(lg1);
      s[i] += p0 + p1;
      ax[i][0] += p0 * xa0 + p1 * xb0;
      ax[i][1] += p0 * xa1 + p1 * xb1;
      ax[i][2] += p0 * xa2 + p1 * xb2;
      unsigned int pk = (unsigned int)f2b(p0) | ((unsigned int)f2b(p1) << 16);
      *(unsigned int*)&Pl[wv][((cl >> 2) * 16 + gq * 4 + i) * 8 +
                              (cl & 3) * 2] = pk;
    }
    // PV (P write->read same wave: compiler inserts lgkmcnt)
    bf16x8 pf = *(const bf16x8*)&Pl[wv][(gq * 16 + cl) * 8];
#pragma unroll
    for (int dt = 0; dt < 16; ++dt) {
      bf16x8 vf = *(const bf16x8*)&Vtl[(dt * 64 + gq * 16 + cl) * 8];
      o[dt] = __builtin_amdgcn_mfma_f32_16x16x32_bf16(pf, vf, o[dt], 0, 0, 0);
    }
  }

  // final reductions over the 16-lane (cl) group
#pragma unroll
  for (int i = 0; i < 4; ++i) {
    float v = s[i];
    v += __shfl_xor(v, 1);
    v += __shfl_xor(v, 2);
    v += __shfl_xor(v, 4);
    v += __shfl_xor(v, 8);
    s[i] = v;
#pragma unroll
    for (int c = 0; c < 3; ++c) {
      float a = ax[i][c];
      a += __shfl_xor(a, 1);
      a += __shfl_xor(a, 2);
      a += __shfl_xor(a, 4);
      a += __shfl_xor(a, 8);
      ax[i][c] = a;
    }
  }
  us* pb = (split < 8) ? plo : phi;
  float* paxb = (split < 8) ? paxlo : paxhi;
  const int sl = split & 7;
  if (cl == 0) {
#pragma unroll
    for (int i = 0; i < 4; ++i) {
      ps[(size_t)split * N_ROWS + rowg[i]] = s[i];
      paxb[((size_t)sl * N_ROWS + rowg[i]) * 3 + 0] = ax[i][0];
      paxb[((size_t)sl * N_ROWS + rowg[i]) * 3 + 1] = ax[i][1];
      paxb[((size_t)sl * N_ROWS + rowg[i]) * 3 + 2] = ax[i][2];
    }
  }
#pragma unroll
  for (int dt = 0; dt < 16; ++dt)
#pragma unroll
    for (int i = 0; i < 4; ++i)
      pb[((size_t)sl * N_ROWS + rowg[i]) * DIM + dt * 16 + cl] =
          f2b(o[dt][i]);
}

// ---------------------------------------------------------------------------
// Merge nsplit raw partials: O = (sum o_k)/(sum s_k); xyz update
// ---------------------------------------------------------------------------
__global__ __launch_bounds__(256) void merge_kernel(
    const us* __restrict__ plo, const us* __restrict__ phi,
    const float* __restrict__ ps, const float* __restrict__ paxlo,
    const float* __restrict__ paxhi, const float* __restrict__ xyzc,
    const float* __restrict__ betap, us* __restrict__ xattb,
    float* __restrict__ xyz_out, int nsplit) {
  const int wvl = threadIdx.x >> 6, lane = threadIdx.x & 63;
  const int row = blockIdx.x * 4 + wvl;
  float den = 0.f;
  for (int k = 0; k < nsplit; ++k) den += ps[(size_t)k * N_ROWS + row];
  float inv = 1.f / den;
  float a0 = 0.f, a1 = 0.f, a2 = 0.f, a3 = 0.f;
  for (int k = 0; k < nsplit; ++k) {
    const us* pb = (k < 8) ? plo : phi;
    const us* p = &pb[((size_t)(k & 7) * N_ROWS + row) * DIM + lane * 4];
    uint2 u = *(const uint2*)p;
    a0 += __uint_as_float((u.x & 0xffffu) << 16);
    a1 += __uint_as_float(u.x & 0xffff0000u);
    a2 += __uint_as_float((u.y & 0xffffu) << 16);
    a3 += __uint_as_float(u.y & 0xffff0000u);
  }
  ushort4 ov;
  ov.x = f2b(a0 * inv);
  ov.y = f2b(a1 * inv);
  ov.z = f2b(a2 * inv);
  ov.w = f2b(a3 * inv);
  *(ushort4*)&xattb[(size_t)row * DIM + lane * 4] = ov;
  if (lane < 3) {
    float axs = 0.f;
    for (int k = 0; k < nsplit; ++k) {
      const float* paxb = (k < 8) ? paxlo : paxhi;
      axs += paxb[((size_t)(k & 7) * N_ROWS + row) * 3 + lane];
    }
    float beta = betap[0];
    xyz_out[(size_t)row * 3 + lane] =
        beta * axs * inv + (1.f - beta) * xyzc[(size_t)row * 3 + lane];
  }
}

// ---------------------------------------------------------------------------
// GraphNorm
// ---------------------------------------------------------------------------
__global__ __launch_bounds__(256) void gn_part_kernel(
    const float* __restrict__ X, const int* __restrict__ cums,
    float* __restrict__ gpart) {
  const int seg = blockIdx.x, chunk = blockIdx.y, d = threadIdx.x;
  const int r0 = cums[seg], r1 = cums[seg + 1];
  const int cnt = r1 - r0;
  const int per = (cnt + GN_CHUNKS - 1) / GN_CHUNKS;
  const int a = r0 + chunk * per;
  const int b = min(a + per, r1);
  float s = 0.f, ss = 0.f;
  for (int r = a; r < b; ++r) {
    float v = X[(size_t)r * DIM + d];
    s += v;
    ss += v * v;
  }
  gpart[(((size_t)seg * GN_CHUNKS + chunk) * 2 + 0) * DIM + d] = s;
  gpart[(((size_t)seg * GN_CHUNKS + chunk) * 2 + 1) * DIM + d] = ss;
}

__global__ void gn_red_kernel(const float* __restrict__ gpart,
                              const int* __restrict__ cums,
                              float* __restrict__ gm, float* __restrict__ gi) {
  const int seg = blockIdx.x, d = threadIdx.x;
  float s = 0.f, ss = 0.f;
#pragma unroll
  for (int c = 0; c < GN_CHUNKS; ++c) {
    s += gpart[(((size_t)seg * GN_CHUNKS + c) * 2 + 0) * DIM + d];
    ss += gpart[(((size_t)seg * GN_CHUNKS + c) * 2 + 1) * DIM + d];
  }
  float cnt = (float)(cums[seg + 1] - cums[seg]);
  float mean = s / fmaxf(cnt, 1.f);
  float var = (ss - cnt * mean * mean) / fmaxf(cnt - 1.f, 1.f);
  gm[seg * DIM + d] = mean;
  gi[seg * DIM + d] = 1.f / (sqrtf(fmaxf(var, 0.f)) + 1e-5f);
}

__global__ __launch_bounds__(256) void gn_apply_kernel(
    const float* __restrict__ X, const float* __restrict__ gamma,
    const float* __restrict__ betag, const int* __restrict__ cums, int nseg,
    const float* __restrict__ gm, const float* __restrict__ gi,
    float* __restrict__ Xout, us* __restrict__ Xb, float* __restrict__ ofinal) {
  int idx = blockIdx.x * 256 + threadIdx.x;
  int base = idx * 4;
  int row = base >> 8, d0 = base & 255;
  int seg = 0;
  for (int b = 1; b <= nseg; ++b) seg += (row >= cums[b]) ? 1 : 0;
  float4 x = ((const float4*)X)[idx];
  float xs[4] = {x.x, x.y, x.z, x.w};
  const float* gmp = gm + seg * DIM + d0;
  const float* gip = gi + seg * DIM + d0;
  float o[4];
#pragma unroll
  for (int c = 0; c < 4; ++c)
    o[c] = gamma[d0 + c] * (xs[c] - gmp[c]) * gip[c] + betag[d0 + c];
  float4 ov = {o[0], o[1], o[2], o[3]};
  ((float4*)Xout)[idx] = ov;
  ushort4 ub;
  ub.x = f2b(o[0]);
  ub.y = f2b(o[1]);
  ub.z = f2b(o[2]);
  ub.w = f2b(o[3]);
  ((ushort4*)Xb)[idx] = ub;
  if (ofinal) ((float4*)ofinal)[idx] = ov;
}

// ---------------------------------------------------------------------------
extern "C" void kernel_launch(void* const* d_in, const int* in_sizes, int n_in,
                              void* d_out, int out_size, void* d_ws,
                              size_t ws_size, hipStream_t stream) {
  const float* xyz0 = (const float*)d_in[0];
  const float* x0 = (const float*)d_in[1];
  const float* yhat = (const float*)d_in[2];
  const int* dmask = (const int*)d_in[3];
  const int* tptr = (const int*)d_in[4];
  const float* bwp = (const float*)d_in[5];
  const float* betap = (const float*)d_in[6];
  const int* cums = (const int*)d_in[7];
  const int* bmask = (const int*)d_in[8];
  const int* usestdp = (const int*)d_in[9];
  const int* selfdp = (const int*)d_in[10];
  const float* qw = (const float*)d_in[11];
  const float* kw = (const float*)d_in[12];
  const float* vw = (const float*)d_in[13];
  const float* ow = (const float*)d_in[14];
  const float* qbv = (const float*)d_in[15];
  const float* kbv = (const float*)d_in[16];
  const float* vbv = (const float*)d_in[17];
  const float* obv = (const float*)d_in[18];
  const float* gamma = (const float*)d_in[19];
  const float* betag = (const float*)d_in[20];
  float* out = (float*)d_out;
  float* ws = (float*)d_ws;

  const size_t ND = (size_t)N_ROWS * DIM;       // 1,048,576
  const size_t WSZ = (size_t)NLAYER * DIM * DIM;
  float* bq = ws + 0 * ND;
  float* bk = ws + 1 * ND;
  float* bv = ws + 2 * ND;
  float* bt = ws + 3 * ND;   // Ktb (bf16) before stats; Q@M f32 after
  float* bh = ws + 4 * ND;   // Qb16 + Kb16
  float* bx = ws + 5 * ND;
  float* Mp = ws + 6 * ND;                       // 8*65536 f32 (hosts Vtb later)
  float* Mm = Mp + 8 * 65536;
  float* kpart = Mm + 65536;
  float* ksum = kpart + 64 * 256;
  float* meanv = ksum + 256;
  float* istdv = meanv + 4096;
  float* gm = istdv + 4096;
  float* gi = gm + 8 * 256;
  float* logy = gi + 8 * 256;
  float* xyzA = logy + 4096;
  float* xyzB = xyzA + 3 * N_ROWS;
  unsigned int* mbits = (unsigned int*)(xyzB + 3 * N_ROWS);   // N*128 u32
  float* psbase = (float*)(mbits + (size_t)N_ROWS * 128);     // 16*N f32
  float* paxlo = psbase + 16 * (size_t)N_ROWS;                // 8*N*3 f32
  float* gpart = paxlo + 8 * (size_t)N_ROWS * 3;              // 65536 f32
  us* Mb16 = (us*)(gpart + 8 * GN_CHUNKS * 2 * DIM);          // 65536 us
  us* qwb = Mb16 + 65536;
  us* kwb = qwb + WSZ;
  us* vwb = kwb + WSZ;
  us* owb = vwb + WSZ;
  us* xinb = owb + WSZ;        // ND us
  us* xattb = xinb + ND;       // ND us
  float* compact_end = (float*)(xattb + ND);
  // optional tail for KSPLIT 16
  us* phi = (us*)compact_end;                       // 8*ND us = 16MB
  float* paxhi = (float*)(phi + 8 * ND);            // 8*N*3 f32
  float* full_end = paxhi + 8 * (size_t)N_ROWS * 3;
  const size_t full_bytes = (size_t)((char*)full_end - (char*)ws);
  const int nsplit = (ws_size >= full_bytes) ? 16 : 8;
  const int cps = N_ROWS / nsplit;

  us* plo = (us*)ws;            // 8 splits over bq..bt (16MB)
  us* Qb16 = (us*)bh;
  us* Kb16 = Qb16 + ND;
  us* Ktb = (us*)bt;            // 2MB inside bt (4MB)
  us* Vtb = (us*)Mp;            // 2MB inside Mp (2MB)
  float* bo = bv;

  const int nseg = in_sizes[7] - 1;

  prep_kernel<<<16, 256, 0, stream>>>(yhat, logy);
  maskpack_kernel<<<65536, 256, 0, stream>>>(dmask, bmask, mbits);
  cvt_f2b_kernel<<<256, 256, 0, stream>>>(qw, qwb);
  cvt_f2b_kernel<<<256, 256, 0, stream>>>(kw, kwb);
  cvt_f2b_kernel<<<256, 256, 0, stream>>>(vw, vwb);
  cvt_f2b_kernel<<<256, 256, 0, stream>>>(ow, owb);
  cvt_f2b_kernel<<<1024, 256, 0, stream>>>(x0, xinb);

  for (int l = 0; l < NLAYER; ++l) {
    const float* xin = (l == 0) ? x0 : bx;
    const float* xyz_in = (l == 0) ? xyz0 : ((l & 1) ? xyzB : xyzA);
    float* xyz_o = (l & 1) ? xyzA : xyzB;
    const size_t wo = (size_t)l * DIM * DIM;

    mfma_qkv_kernel<<<dim3(64, 4, 3), 256, 0, stream>>>(
        xinb, qwb + wo, kwb + wo, vwb + wo, qbv + l * DIM, kbv + l * DIM,
        vbv + l * DIM, bq, bk, bv, Qb16, Kb16);
    ksum_part_kernel<<<64, 256, 0, stream>>>(bk, kpart);
    ksum_red_kernel<<<1, 256, 0, stream>>>(kpart, ksum);
    vt_kernel<<<dim3(64, 4), 256, 0, stream>>>(bk, Ktb);
    mpart_mfma_kernel<<<dim3(4, 4, 8), 256, 0, stream>>>(Ktb, Mp);
    mreduce_kernel<<<256, 256, 0, stream>>>(Mp, Mm, Mb16);
    mfma_nt_kernel<<<dim3(64, 4), 256, 0, stream>>>(Qb16, Mb16, nullptr,
                                                    nullptr, bt, nullptr);
    stats_kernel<<<1024, 256, 0, stream>>>(bq, bt, ksum, tptr, meanv, istdv);
    vt_kernel<<<dim3(64, 4), 256, 0, stream>>>(bv, Vtb);  // Mp dead now
    flash3_kernel<<<dim3(64, nsplit), 256, 0, stream>>>(
        Qb16, Kb16, Vtb, xyz_in, logy, meanv, istdv, mbits, tptr, bwp, usestdp,
        selfdp, plo, phi, psbase, paxlo, paxhi, cps);
    merge_kernel<<<1024, 256, 0, stream>>>(plo, phi, psbase, paxlo, paxhi,
                                           xyz_in, betap, xattb, xyz_o,
                                           nsplit);
    mfma_nt_kernel<<<dim3(64, 4), 256, 0, stream>>>(xattb, owb + wo,
                                                    obv + l * DIM, xin, bo,
                                                    nullptr);
    gn_part_kernel<<<dim3(nseg, GN_CHUNKS), 256, 0, stream>>>(bo, cums, gpart);
    gn_red_kernel<<<nseg, 256, 0, stream>>>(gpart, cums, gm, gi);
    gn_apply_kernel<<<1024, 256, 0, stream>>>(
        bo, gamma + (size_t)l * DIM, betag + (size_t)l * DIM, cums, nseg, gm,
        gi, bx, xinb, (l == NLAYER - 1) ? out : nullptr);
  }
}